// Round 6
// baseline (13926.463 us; speedup 1.0000x reference)
//
#include <hip/hip_runtime.h>
#include <cstdint>

typedef __bf16 bf16_t;
typedef __attribute__((ext_vector_type(8))) __bf16 bf16x8;
typedef __attribute__((ext_vector_type(4))) float f32x4;

#define TOKENS 26896
#define LLEN   1681
#define SDIM   41
#define EDIM   768

// ---------------- async global->LDS 16B ----------------
__device__ __forceinline__ void gload_lds16(const bf16_t* g, bf16_t* l) {
  auto gp = reinterpret_cast<const __attribute__((address_space(1))) char*>(
      reinterpret_cast<uintptr_t>(g));
  auto lp = reinterpret_cast<__attribute__((address_space(3))) char*>(
      reinterpret_cast<uintptr_t>(l));
  __builtin_amdgcn_global_load_lds(gp, lp, 16, 0, 0);
}

enum { EPI_T_POS = 0, EPI_BF16 = 1, EPI_ADD_T = 2, EPI_GELU = 3, EPI_F32 = 4 };

// ============================================================================
// gemm8: C = A(MxK,bf16) @ Bt(NxK,bf16)^T
// 128x256 tile, BK=64, 512 thr (8 waves = 2M x 4N, 64x64 per wave).
// Ring-3 LDS (3 x 48KB = 144KB), counted vmcnt(6) at tile boundaries (T4),
// 2 phases per K-tile with raw-barrier MFMA bursts (T3), XOR-swizzled LDS
// rows (T2, phys16Bslot = k_slot ^ (row&7), both-sides), setprio (T5),
// XCD chunked swizzle + row-major tile order (T1 / A-panel L2 reuse).
// Slot layout (bf16 elems): A[128][64] at 0, B[256][64] at 8192; slot
// stride 24576. Stage: thread tid covers row (p*64 + tid>>3), 16B phys slot
// (tid&7); dest = slotbase (+8192 for B) + p*4096 + tid*8  (lane-linear).
// ============================================================================
template <int EPI>
__global__ __launch_bounds__(512, 1) void gemm8_kernel(
    const bf16_t* __restrict__ A, const bf16_t* __restrict__ Bt,
    const float* __restrict__ bias, float* __restrict__ fout,
    bf16_t* __restrict__ bout, const float* __restrict__ pos,
    int M, int N, int K, int ntn, int nwg)
{
  extern __shared__ bf16_t lds[];
  const int tid = threadIdx.x, wave = tid >> 6, lane = tid & 63;
  const int wr = wave >> 2, wc = wave & 3;   // 2 x 4 waves, 64x64 each

  // T1: bijective XCD chunked swizzle (m204)
  int id = blockIdx.x;
  {
    const int q = nwg >> 3, r = nwg & 7;
    const int xcd = id & 7, ix = id >> 3;
    id = (xcd < r ? xcd * (q + 1) : r * (q + 1) + (xcd - r) * q) + ix;
  }
  const int row0 = (id / ntn) * 128;   // row-major over col-tiles: A L2 reuse
  const int col0 = (id % ntn) * 256;
  const int NT = K >> 6;

  // ---- staging: per load, thread -> row = p*64 + (tid>>3), phys slot tid&7
  const int srow = tid >> 3;                       // 0..63
  const int scol = (((tid & 7) ^ (srow & 7)) << 3);  // inverse-swizzled src col
  const bf16_t* aptr[2];
  const bf16_t* bptr[4];
  #pragma unroll
  for (int p = 0; p < 2; ++p) {
    int ar = row0 + p * 64 + srow; if (ar > M - 1) ar = M - 1;
    aptr[p] = A + (size_t)ar * K + scol;
  }
  #pragma unroll
  for (int p = 0; p < 4; ++p) {
    int br = col0 + p * 64 + srow; if (br > N - 1) br = N - 1;
    bptr[p] = Bt + (size_t)br * K + scol;
  }
  bf16_t* sdst = lds + tid * 8;

  #define STA(SL, KO, P) gload_lds16(aptr[P] + (KO), sdst + (SL) * 24576 + (P) * 4096)
  #define STB(SL, KO, P) gload_lds16(bptr[P] + (KO), sdst + (SL) * 24576 + 8192 + (P) * 4096)

  const int l15 = lane & 15, l4 = lane >> 4, x7 = l15 & 7;
  f32x4 acc[4][4] = {};

  // phase: ds_read 8 frags (ks half) + stage-issue + barrier + MFMA burst
  #define PHASE(SB, KS, STBLK, TAIL)                                          \
  do {                                                                        \
    bf16x8 fa[4], fb[4];                                                      \
    _Pragma("unroll")                                                         \
    for (int m_ = 0; m_ < 4; ++m_)                                            \
      fa[m_] = *(const bf16x8*)((SB) + (wr * 64 + m_ * 16 + l15) * 64 +       \
                                (((((KS) << 2) | l4)) ^ x7) * 8);             \
    _Pragma("unroll")                                                         \
    for (int n_ = 0; n_ < 4; ++n_)                                            \
      fb[n_] = *(const bf16x8*)((SB) + 8192 + (wc * 64 + n_ * 16 + l15) * 64 +\
                                (((((KS) << 2) | l4)) ^ x7) * 8);             \
    STBLK;                                                                    \
    __builtin_amdgcn_s_barrier();                                             \
    asm volatile("s_waitcnt lgkmcnt(0)" ::: "memory");                        \
    __builtin_amdgcn_sched_barrier(0);                                        \
    __builtin_amdgcn_s_setprio(1);                                            \
    _Pragma("unroll")                                                         \
    for (int m_ = 0; m_ < 4; ++m_)                                            \
      _Pragma("unroll")                                                       \
      for (int n_ = 0; n_ < 4; ++n_)                                          \
        acc[m_][n_] = __builtin_amdgcn_mfma_f32_16x16x32_bf16(                \
            fa[m_], fb[n_], acc[m_][n_], 0, 0, 0);                            \
    __builtin_amdgcn_s_setprio(0);                                            \
    TAIL;                                                                     \
    __builtin_amdgcn_s_barrier();                                             \
  } while (0)

  // ---- prologue: stage tiles 0,1; retire tile 0; publish ----
  STA(0, 0, 0); STA(0, 0, 1);
  STB(0, 0, 0); STB(0, 0, 1); STB(0, 0, 2); STB(0, 0, 3);
  if (NT > 1) {
    STA(1, 64, 0); STA(1, 64, 1);
    STB(1, 64, 0); STB(1, 64, 1); STB(1, 64, 2); STB(1, 64, 3);
    asm volatile("s_waitcnt vmcnt(6)" ::: "memory");
  } else {
    asm volatile("s_waitcnt vmcnt(0)" ::: "memory");
  }
  __builtin_amdgcn_s_barrier();

  // ---- main loop: compute tile t from slot s, stage tile t+2 into slot s2 ----
  int s = 0, s2 = 2, koff2 = 128;
  for (int t = 0; t < NT; ++t) {
    bf16_t* sb = lds + s * 24576;
    if (t + 2 < NT) {
      PHASE(sb, 0, { STA(s2, koff2, 0); STA(s2, koff2, 1); STB(s2, koff2, 0); }, {});
      PHASE(sb, 1, { STB(s2, koff2, 1); STB(s2, koff2, 2); STB(s2, koff2, 3); },
            { asm volatile("s_waitcnt vmcnt(6)" ::: "memory"); });
    } else if (t + 1 < NT) {
      PHASE(sb, 0, {}, {});
      PHASE(sb, 1, {}, { asm volatile("s_waitcnt vmcnt(0)" ::: "memory"); });
    } else {
      PHASE(sb, 0, {}, {});
      PHASE(sb, 1, {}, {});
    }
    s = (s == 2) ? 0 : s + 1;
    s2 = (s2 == 2) ? 0 : s2 + 1;
    koff2 += 64;
  }
  #undef PHASE
  #undef STA
  #undef STB

  // ---- epilogue: D row = (lane>>4)*4 + r, col = lane&15 (m89 layout) ----
  const int rgrp = lane >> 4;
  #pragma unroll
  for (int m = 0; m < 4; ++m) {
    #pragma unroll
    for (int n = 0; n < 4; ++n) {
      const int col = col0 + wc * 64 + n * 16 + l15;
      if (col >= N) continue;
      const int rbase = row0 + wr * 64 + m * 16 + rgrp * 4;
      float bv = 0.f;
      if constexpr (EPI != EPI_F32) bv = bias[col];
      #pragma unroll
      for (int r = 0; r < 4; ++r) {
        const int rr = rbase + r;
        if (rr >= M) continue;
        const float v = acc[m][n][r] + bv;
        const size_t o = (size_t)rr * N + col;
        if constexpr (EPI == EPI_T_POS) {
          const int l = rr % LLEN;
          fout[o] = v + pos[(size_t)l * N + col];
        } else if constexpr (EPI == EPI_BF16) {
          bout[o] = (bf16_t)v;
        } else if constexpr (EPI == EPI_ADD_T) {
          fout[o] += v;
        } else if constexpr (EPI == EPI_GELU) {
          const float gg = 0.5f * v * (1.f + erff(v * 0.70710678118654752f));
          bout[o] = (bf16_t)gg;
        } else {
          fout[o] = v;
        }
      }
    }
  }
}

// ---------------- head GEMM (N=100), simple 128x128 ----------------
__global__ __launch_bounds__(256) void gemm128_f32(
    const bf16_t* __restrict__ A, const bf16_t* __restrict__ Bt,
    float* __restrict__ fout, int M, int N, int K)
{
  __shared__ bf16_t As[128 * 32];
  __shared__ bf16_t Bs[128 * 32];
  const int tid = threadIdx.x, wave = tid >> 6, lane = tid & 63;
  const int row0 = blockIdx.x * 128, col0 = blockIdx.y * 128;
  const int wr = wave >> 1, wc = wave & 1;
  f32x4 acc[4][4] = {};
  const int srow = lane >> 2, skoff = (lane & 3) * 8;
  const int nsteps = K >> 5;
  for (int kt = 0; kt < nsteps; ++kt) {
    const int k0 = kt << 5;
    #pragma unroll
    for (int i = 0; i < 2; ++i) {
      const int r = (i * 4 + wave) * 16 + srow;
      int arow = row0 + r; if (arow > M - 1) arow = M - 1;
      int brow = col0 + r; if (brow > N - 1) brow = N - 1;
      gload_lds16(A  + (size_t)arow * K + k0 + skoff, &As[r * 32 + skoff]);
      gload_lds16(Bt + (size_t)brow * K + k0 + skoff, &Bs[r * 32 + skoff]);
    }
    asm volatile("s_waitcnt vmcnt(0)" ::: "memory");
    __syncthreads();
    const int lrow = lane & 15, lk = (lane >> 4) * 8;
    bf16x8 af[4], bfr[4];
    #pragma unroll
    for (int mi = 0; mi < 4; ++mi)
      af[mi] = *(const bf16x8*)&As[(wr * 64 + mi * 16 + lrow) * 32 + lk];
    #pragma unroll
    for (int ni = 0; ni < 4; ++ni)
      bfr[ni] = *(const bf16x8*)&Bs[(wc * 64 + ni * 16 + lrow) * 32 + lk];
    #pragma unroll
    for (int mi = 0; mi < 4; ++mi)
      #pragma unroll
      for (int ni = 0; ni < 4; ++ni)
        acc[mi][ni] = __builtin_amdgcn_mfma_f32_16x16x32_bf16(af[mi], bfr[ni], acc[mi][ni], 0, 0, 0);
    __syncthreads();
  }
  const int lcol = lane & 15, rgrp = lane >> 4;
  #pragma unroll
  for (int mi = 0; mi < 4; ++mi)
    #pragma unroll
    for (int ni = 0; ni < 4; ++ni) {
      const int col = col0 + wc * 64 + ni * 16 + lcol;
      if (col >= N) continue;
      const int rbase = row0 + wr * 64 + mi * 16 + rgrp * 4;
      #pragma unroll
      for (int r = 0; r < 4; ++r) {
        const int rr = rbase + r;
        if (rr >= M) continue;
        fout[(size_t)rr * N + col] = acc[mi][ni][r];
      }
    }
}

// ---------------- LayerNorm: one wave per token, E=768 ----------------
__global__ __launch_bounds__(256) void ln_kernel(
    const float* __restrict__ t, const float* __restrict__ w,
    const float* __restrict__ b, bf16_t* __restrict__ y)
{
  const int token = blockIdx.x * 4 + (threadIdx.x >> 6);
  const int lane  = threadIdx.x & 63;
  const float* xp = t + (size_t)token * EDIM;
  float v[12];
  float s = 0.f;
  #pragma unroll
  for (int i = 0; i < 12; ++i) { v[i] = xp[lane + i * 64]; s += v[i]; }
  #pragma unroll
  for (int off = 32; off; off >>= 1) s += __shfl_xor(s, off);
  const float mu = s * (1.f / 768.f);
  float q = 0.f;
  #pragma unroll
  for (int i = 0; i < 12; ++i) { const float d = v[i] - mu; q += d * d; }
  #pragma unroll
  for (int off = 32; off; off >>= 1) q += __shfl_xor(q, off);
  const float rs = rsqrtf(q * (1.f / 768.f) + 1e-6f);
  bf16_t* yp = y + (size_t)token * EDIM;
  #pragma unroll
  for (int i = 0; i < 12; ++i) {
    const int e = lane + i * 64;
    yp[e] = (bf16_t)((v[i] - mu) * rs * w[e] + b[e]);
  }
}

// ---------------- row-wise attention: block per (b_local, s1, h) -----------
__global__ __launch_bounds__(256) void attn_kernel(
    const bf16_t* __restrict__ qkv, bf16_t* __restrict__ o)
{
  const int blk = blockIdx.x;
  const int h  = blk % 12;
  const int bs = blk / 12;
  const int s1 = bs % SDIM;
  const int b  = bs / SDIM;
  __shared__ float Qs[SDIM][65], Ks[SDIM][65], Vs[SDIM][65], Ps[SDIM][42];
  const int tid = threadIdx.x;
  const size_t base = ((size_t)b * LLEN + (size_t)s1 * SDIM);

  for (int idx = tid; idx < SDIM * 64; idx += 256) {
    const int m = idx >> 6, d = idx & 63;
    const bf16_t* p = qkv + (base + m) * 2304 + h * 64 + d;
    Qs[m][d] = (float)p[0];
    Ks[m][d] = (float)p[768];
    Vs[m][d] = (float)p[1536];
  }
  __syncthreads();

  for (int idx = tid; idx < SDIM * SDIM; idx += 256) {
    const int n = idx / SDIM, m = idx % SDIM;
    float s = 0.f;
    #pragma unroll
    for (int d = 0; d < 64; ++d) s += Qs[n][d] * Ks[m][d];
    Ps[n][m] = s * 0.125f;
  }
  __syncthreads();

  if (tid < SDIM) {
    float mx = -1e30f;
    for (int m = 0; m < SDIM; ++m) mx = fmaxf(mx, Ps[tid][m]);
    float sum = 0.f;
    for (int m = 0; m < SDIM; ++m) { const float e = __expf(Ps[tid][m] - mx); Ps[tid][m] = e; sum += e; }
    const float inv = 1.f / sum;
    for (int m = 0; m < SDIM; ++m) Ps[tid][m] *= inv;
  }
  __syncthreads();

  for (int idx = tid; idx < SDIM * 64; idx += 256) {
    const int n = idx >> 6, d = idx & 63;
    float s = 0.f;
    #pragma unroll
    for (int m = 0; m < SDIM; ++m) s += Ps[n][m] * Vs[m][d];
    o[(base + n) * EDIM + h * 64 + d] = (bf16_t)s;
  }
}

// ---------------- transpose fp32(KxN) -> bf16(NxK) ----------------
__global__ __launch_bounds__(256) void transpose_kernel(
    const float* __restrict__ in, bf16_t* __restrict__ out, int K, int N)
{
  __shared__ float tile[32][33];
  const int k0 = blockIdx.x * 32, n0 = blockIdx.y * 32;
  const int tx = threadIdx.x & 31, ty = threadIdx.x >> 5;
  #pragma unroll
  for (int i = 0; i < 32; i += 8) {
    const int k = k0 + ty + i, n = n0 + tx;
    if (k < K && n < N) tile[ty + i][tx] = in[(size_t)k * N + n];
  }
  __syncthreads();
  #pragma unroll
  for (int i = 0; i < 32; i += 8) {
    const int n = n0 + ty + i, k = k0 + tx;
    if (n < N && k < K) out[(size_t)n * K + k] = (bf16_t)tile[tx][ty + i];
  }
}

// ---------------- im2col for conv1 chunk (pad K 1200->1216) ----------------
__global__ __launch_bounds__(256) void im2col_kernel(
    const float* __restrict__ x, bf16_t* __restrict__ col, int tok0, int ntok)
{
  const size_t idx = (size_t)blockIdx.x * 256 + threadIdx.x;
  if (idx >= (size_t)ntok * 1216) return;
  const int kk = (int)(idx % 1216);
  const size_t tok = tok0 + idx / 1216;
  const int b = (int)(tok / LLEN), l = (int)(tok % LLEN);
  const int s1 = l / SDIM, s2 = l % SDIM;
  float v = 0.f;
  if (kk < 1200) {
    const int cin = kk / 100, r = kk % 100, ky = r / 10, kx = r % 10;
    const int iy = s1 - 5 + ky, ix = s2 - 5 + kx;
    if (iy >= 0 && iy < 40 && ix >= 0 && ix < 40)
      v = x[((size_t)(b * 12 + cin) * 40 + iy) * 40 + ix];
  }
  col[idx] = (bf16_t)v;
}

__global__ __launch_bounds__(256) void convw_kernel(
    const float* __restrict__ w, bf16_t* __restrict__ out)
{
  const int idx = blockIdx.x * 256 + threadIdx.x;
  const int kk = idx % 1216, e = idx / 1216;
  const float v = (kk < 1200) ? w[(size_t)e * 1200 + kk] : 0.f;
  out[idx] = (bf16_t)v;
}

__global__ __launch_bounds__(256) void tconvw_kernel(
    const float* __restrict__ w, bf16_t* __restrict__ out)
{
  const int idx = blockIdx.x * 256 + threadIdx.x;  // 100*768
  const int e = idx % 768, tap = idx / 768;
  const int ky = tap / 10, kx = tap % 10;
  out[idx] = (bf16_t)w[(size_t)e * 100 + (9 - ky) * 10 + (9 - kx)];
}

// ---------------- final gather ----------------
__global__ __launch_bounds__(256) void outconv_kernel(
    const float* __restrict__ g, const float* __restrict__ tb,
    float* __restrict__ out)
{
  const int idx = blockIdx.x * 256 + threadIdx.x;
  if (idx >= 16 * 40 * 40) return;
  const int x = idx % 40, y = (idx / 40) % 40, b = idx / 1600;
  float s = tb[0];
  #pragma unroll
  for (int ky = 0; ky < 10; ++ky) {
    const int ty_ = y - 4 + ky;
    if (ty_ < 0 || ty_ >= SDIM) continue;
    #pragma unroll
    for (int kx = 0; kx < 10; ++kx) {
      const int tx_ = x - 4 + kx;
      if (tx_ < 0 || tx_ >= SDIM) continue;
      s += g[((size_t)b * LLEN + ty_ * SDIM + tx_) * 100 + ky * 10 + kx];
    }
  }
  out[idx] = s;
}

// ============================================================================
extern "C" void kernel_launch(void* const* d_in, const int* in_sizes, int n_in,
                              void* d_out, int out_size, void* d_ws, size_t ws_size,
                              hipStream_t stream)
{
  const float* x       = (const float*)d_in[0];
  const float* conv_w  = (const float*)d_in[1];
  const float* conv_b  = (const float*)d_in[2];
  const float* pos     = (const float*)d_in[3];
  const float* ln1_w   = (const float*)d_in[4];
  const float* ln1_b   = (const float*)d_in[5];
  const float* qkv_w   = (const float*)d_in[6];
  const float* qkv_b   = (const float*)d_in[7];
  const float* proj_w  = (const float*)d_in[8];
  const float* proj_b  = (const float*)d_in[9];
  const float* ln2_w   = (const float*)d_in[10];
  const float* ln2_b   = (const float*)d_in[11];
  const float* fc1_w   = (const float*)d_in[12];
  const float* fc1_b   = (const float*)d_in[13];
  const float* fc2_w   = (const float*)d_in[14];
  const float* fc2_b   = (const float*)d_in[15];
  const float* lnf_w   = (const float*)d_in[16];
  const float* lnf_b   = (const float*)d_in[17];
  const float* tconv_w = (const float*)d_in[18];
  const float* tconv_b = (const float*)d_in[19];
  float* out = (float*)d_out;

  constexpr int LDS8 = 3 * 24576 * 2;  // 147456 B ring-3
  hipFuncSetAttribute((const void*)gemm8_kernel<EPI_T_POS>, hipFuncAttributeMaxDynamicSharedMemorySize, LDS8);
  hipFuncSetAttribute((const void*)gemm8_kernel<EPI_BF16 >, hipFuncAttributeMaxDynamicSharedMemorySize, LDS8);
  hipFuncSetAttribute((const void*)gemm8_kernel<EPI_ADD_T>, hipFuncAttributeMaxDynamicSharedMemorySize, LDS8);
  hipFuncSetAttribute((const void*)gemm8_kernel<EPI_GELU >, hipFuncAttributeMaxDynamicSharedMemorySize, LDS8);

  // ---- workspace: pick chunking from ws_size ----
  const size_t need2 = 14155776UL + 82624512UL + 41312256UL + 82624512UL + 2048UL;
  const int nch = (ws_size >= need2) ? 2 : 4;
  const int cht = TOKENS / nch;          // 13448 or 6724

  char* p = (char*)d_ws;
  auto alloc = [&](size_t bytes) {
    char* r = p;
    p += (bytes + 255) & ~(size_t)255;
    return r;
  };
  bf16_t* wbuf = (bf16_t*)alloc((size_t)768 * 9216 * 2);
  float*  t    = (float*)alloc((size_t)TOKENS * EDIM * 4);
  bf16_t* ybuf = (bf16_t*)alloc((size_t)TOKENS * EDIM * 2);
  bf16_t* hbuf = (bf16_t*)alloc((size_t)cht * 3072 * 2);

  bf16_t* Wq = wbuf;
  bf16_t* Wp = Wq + (size_t)2304 * 768;
  bf16_t* W1 = Wp + (size_t)768 * 768;
  bf16_t* W2 = W1 + (size_t)3072 * 768;

  auto g8 = [&](int epi, const bf16_t* A, const bf16_t* Bt,
                const float* bias, float* fo, bf16_t* bo, const float* pe,
                int M, int N, int K) {
    const int mtiles = (M + 127) / 128;
    const int ntn = N / 256;
    const int nwg = mtiles * ntn;
    switch (epi) {
      case EPI_T_POS: gemm8_kernel<EPI_T_POS><<<nwg, 512, LDS8, stream>>>(A, Bt, bias, fo, bo, pe, M, N, K, ntn, nwg); break;
      case EPI_BF16:  gemm8_kernel<EPI_BF16 ><<<nwg, 512, LDS8, stream>>>(A, Bt, bias, fo, bo, pe, M, N, K, ntn, nwg); break;
      case EPI_ADD_T: gemm8_kernel<EPI_ADD_T><<<nwg, 512, LDS8, stream>>>(A, Bt, bias, fo, bo, pe, M, N, K, ntn, nwg); break;
      default:        gemm8_kernel<EPI_GELU ><<<nwg, 512, LDS8, stream>>>(A, Bt, bias, fo, bo, pe, M, N, K, ntn, nwg); break;
    }
  };

  // ---- conv1 as chunked im2col GEMM -> t (+bias +pos_embed) ----
  convw_kernel<<<(768 * 1216) / 256, 256, 0, stream>>>(conv_w, wbuf);
  for (int c = 0; c < nch; ++c) {
    const int tok0 = c * cht;
    im2col_kernel<<<(unsigned)(((size_t)cht * 1216 + 255) / 256), 256, 0, stream>>>(x, hbuf, tok0, cht);
    g8(EPI_T_POS, hbuf, wbuf, conv_b, t + (size_t)tok0 * EDIM, nullptr, pos, cht, EDIM, 1216);
  }

  // ---- transformer layers ----
  for (int i = 0; i < 12; ++i) {
    transpose_kernel<<<dim3(24, 72), 256, 0, stream>>>(qkv_w + (size_t)i * 768 * 2304, Wq, 768, 2304);
    transpose_kernel<<<dim3(24, 24), 256, 0, stream>>>(proj_w + (size_t)i * 768 * 768, Wp, 768, 768);
    transpose_kernel<<<dim3(24, 96), 256, 0, stream>>>(fc1_w + (size_t)i * 768 * 3072, W1, 768, 3072);
    transpose_kernel<<<dim3(96, 24), 256, 0, stream>>>(fc2_w + (size_t)i * 3072 * 768, W2, 3072, 768);

    ln_kernel<<<TOKENS / 4, 256, 0, stream>>>(t, ln1_w + i * EDIM, ln1_b + i * EDIM, ybuf);
    for (int c = 0; c < nch; ++c) {
      const size_t ro = (size_t)c * cht;
      g8(EPI_BF16, ybuf + ro * EDIM, Wq, qkv_b + i * 2304, nullptr, hbuf, nullptr, cht, 2304, 768);
      attn_kernel<<<(16 / nch) * SDIM * 12, 256, 0, stream>>>(hbuf, ybuf + ro * EDIM);
    }
    g8(EPI_ADD_T, ybuf, Wp, proj_b + i * EDIM, t, nullptr, nullptr, TOKENS, EDIM, 768);

    ln_kernel<<<TOKENS / 4, 256, 0, stream>>>(t, ln2_w + i * EDIM, ln2_b + i * EDIM, ybuf);
    for (int c = 0; c < nch; ++c) {
      const size_t ro = (size_t)c * cht;
      g8(EPI_GELU, ybuf + ro * EDIM, W1, fc1_b + i * 3072, nullptr, hbuf, nullptr, cht, 3072, 768);
      g8(EPI_ADD_T, hbuf, W2, fc2_b + i * EDIM, t + ro * EDIM, nullptr, nullptr, cht, EDIM, 3072);
    }
  }

  // ---- final LN + tconv head ----
  ln_kernel<<<TOKENS / 4, 256, 0, stream>>>(t, lnf_w, lnf_b, ybuf);
  tconvw_kernel<<<(100 * 768) / 256, 256, 0, stream>>>(tconv_w, wbuf);
  gemm128_f32<<<dim3((TOKENS + 127) / 128, 1), 256, 0, stream>>>(ybuf, wbuf, (float*)hbuf, TOKENS, 100, 768);
  outconv_kernel<<<100, 256, 0, stream>>>((const float*)hbuf, tconv_b, out);
}

// Round 7
// 12254.891 us; speedup vs baseline: 1.1364x; 1.1364x over previous
//
#include <hip/hip_runtime.h>
#include <cstdint>

typedef __bf16 bf16_t;
typedef __attribute__((ext_vector_type(8))) __bf16 bf16x8;
typedef __attribute__((ext_vector_type(4))) float f32x4;

#define TOKENS 26896
#define LLEN   1681
#define SDIM   41
#define EDIM   768

// ---------------- async global->LDS 16B ----------------
__device__ __forceinline__ void gload_lds16(const bf16_t* g, bf16_t* l) {
  auto gp = reinterpret_cast<const __attribute__((address_space(1))) char*>(
      reinterpret_cast<uintptr_t>(g));
  auto lp = reinterpret_cast<__attribute__((address_space(3))) char*>(
      reinterpret_cast<uintptr_t>(l));
  __builtin_amdgcn_global_load_lds(gp, lp, 16, 0, 0);
}

enum { EPI_T_POS = 0, EPI_BF16 = 1, EPI_ADD_T = 2, EPI_GELU = 3, EPI_F32 = 4 };

// ============================================================================
// gemm5: C = A(MxK,bf16) @ Bt(NxK,bf16)^T
// BM=256 x BN (256 or 128), BK=64, 512 thr (8 waves).
//   BN=256: waves 2Mx4N (wave 128x64, 64 MFMA/barrier), LDS 128KB dbuf.
//   BN=128: waves 4Mx2N (wave  64x64, 32 MFMA/barrier), LDS  96KB dbuf.
// Simple 2-phase (stage next buf -> compute cur -> __syncthreads), dbuf
// parity compile-time via unroll-by-2 (R6 lesson: no runtime slot indices).
// XOR swizzle: phys 16B-slot = k16 ^ (row&7), both sides (0 conflicts
// measured R3/R5 for the 4-slot analog; 8-slot spreads 64 lanes over all 32
// banks). Row-major tile order + bijective XCD swizzle (A-panel L2 reuse).
// ============================================================================
template <int BN, int EPI>
__global__ __launch_bounds__(512, 1) void gemm5_kernel(
    const bf16_t* __restrict__ A, const bf16_t* __restrict__ Bt,
    const float* __restrict__ bias, float* __restrict__ fout,
    bf16_t* __restrict__ bout, const float* __restrict__ pos,
    int M, int N, int K, int ntn, int nwg)
{
  constexpr int NWC   = BN / 64;        // waves along N
  constexpr int MW    = 2 * NWC;        // m-frags per wave
  constexpr int WROWS = 32 * NWC;       // rows per wave
  constexpr int BP    = BN / 64;        // B staging passes
  constexpr int SLOT  = 16384 + BN * 64;  // elems per ring buffer
  extern __shared__ bf16_t lds[];
  const int tid = threadIdx.x, wave = tid >> 6, lane = tid & 63;
  const int wr = wave / NWC, wc = wave % NWC;

  // T1: bijective XCD chunked swizzle (m204)
  int id = blockIdx.x;
  {
    const int q = nwg >> 3, r = nwg & 7;
    const int xcd = id & 7, ix = id >> 3;
    id = (xcd < r ? xcd * (q + 1) : r * (q + 1) + (xcd - r) * q) + ix;
  }
  const int row0 = (id / ntn) * 256;
  const int col0 = (id % ntn) * BN;
  const int NT = K >> 6;

  // ---- staging: thread covers row (p*64 + tid>>3), phys 16B-slot (tid&7)
  const int srow = tid >> 3;                          // 0..63
  const int scol = (((tid & 7) ^ (srow & 7)) << 3);   // inverse-swizzled src
  const bf16_t* aptr[4];
  const bf16_t* bptr[BP];
  #pragma unroll
  for (int p = 0; p < 4; ++p) {
    int ar = row0 + p * 64 + srow; if (ar > M - 1) ar = M - 1;
    aptr[p] = A + (size_t)ar * K + scol;
  }
  #pragma unroll
  for (int p = 0; p < BP; ++p) {
    int br = col0 + p * 64 + srow; if (br > N - 1) br = N - 1;
    bptr[p] = Bt + (size_t)br * K + scol;
  }
  bf16_t* sdst = lds + tid * 8;

  #define STAGE(BUF, KT) do {                                           \
    const int ko_ = (KT) << 6;                                          \
    _Pragma("unroll")                                                   \
    for (int p_ = 0; p_ < 4; ++p_)                                      \
      gload_lds16(aptr[p_] + ko_, sdst + (BUF) * SLOT + p_ * 4096);     \
    _Pragma("unroll")                                                   \
    for (int p_ = 0; p_ < BP; ++p_)                                     \
      gload_lds16(bptr[p_] + ko_, sdst + (BUF) * SLOT + 16384 + p_ * 4096); \
  } while (0)

  // ---- fragment bases (per K=32 half ks): base + compile-time immediates
  const int l15 = lane & 15, l4 = lane >> 4, x7 = l15 & 7;
  const bf16_t* lA[2];
  const bf16_t* lB[2];
  #pragma unroll
  for (int ks = 0; ks < 2; ++ks) {
    lA[ks] = lds + (wr * WROWS + l15) * 64 + ((((ks << 2) | l4)) ^ x7) * 8;
    lB[ks] = lds + 16384 + (wc * 64 + l15) * 64 + ((((ks << 2) | l4)) ^ x7) * 8;
  }

  f32x4 acc[MW][4] = {};

  #define COMPUTE(BUF) do {                                             \
    _Pragma("unroll")                                                   \
    for (int ks_ = 0; ks_ < 2; ++ks_) {                                 \
      bf16x8 fa[MW], fb[4];                                             \
      _Pragma("unroll")                                                 \
      for (int m_ = 0; m_ < MW; ++m_)                                   \
        fa[m_] = *(const bf16x8*)(lA[ks_] + (BUF) * SLOT + m_ * 1024);  \
      _Pragma("unroll")                                                 \
      for (int n_ = 0; n_ < 4; ++n_)                                    \
        fb[n_] = *(const bf16x8*)(lB[ks_] + (BUF) * SLOT + n_ * 1024);  \
      _Pragma("unroll")                                                 \
      for (int m_ = 0; m_ < MW; ++m_)                                   \
        _Pragma("unroll")                                               \
        for (int n_ = 0; n_ < 4; ++n_)                                  \
          acc[m_][n_] = __builtin_amdgcn_mfma_f32_16x16x32_bf16(        \
              fa[m_], fb[n_], acc[m_][n_], 0, 0, 0);                    \
    }                                                                   \
  } while (0)

  // ---- 2-phase main loop (handles odd NT via tail) ----
  STAGE(0, 0);
  __syncthreads();
  int kt = 0;
  while (kt + 2 <= NT) {
    if (kt + 1 < NT) STAGE(1, kt + 1);
    COMPUTE(0);
    __syncthreads();
    if (kt + 2 < NT) STAGE(0, kt + 2);
    COMPUTE(1);
    __syncthreads();
    kt += 2;
  }
  if (kt < NT) COMPUTE(0);
  #undef STAGE
  #undef COMPUTE

  // ---- epilogue: D row = (lane>>4)*4 + r, col = lane&15 (m89 layout) ----
  const int rgrp = lane >> 4;
  #pragma unroll
  for (int m = 0; m < MW; ++m) {
    #pragma unroll
    for (int n = 0; n < 4; ++n) {
      const int col = col0 + wc * 64 + n * 16 + l15;
      if (col >= N) continue;
      const int rbase = row0 + wr * WROWS + m * 16 + rgrp * 4;
      float bv = 0.f;
      if constexpr (EPI != EPI_F32) bv = bias[col];
      #pragma unroll
      for (int r = 0; r < 4; ++r) {
        const int rr = rbase + r;
        if (rr >= M) continue;
        const float v = acc[m][n][r] + bv;
        const size_t o = (size_t)rr * N + col;
        if constexpr (EPI == EPI_T_POS) {
          const int l = rr % LLEN;
          fout[o] = v + pos[(size_t)l * N + col];
        } else if constexpr (EPI == EPI_BF16) {
          bout[o] = (bf16_t)v;
        } else if constexpr (EPI == EPI_ADD_T) {
          fout[o] += v;
        } else if constexpr (EPI == EPI_GELU) {
          const float gg = 0.5f * v * (1.f + erff(v * 0.70710678118654752f));
          bout[o] = (bf16_t)gg;
        } else {
          fout[o] = v;
        }
      }
    }
  }
}

// ---------------- head GEMM (N=100), simple 128x128 ----------------
__global__ __launch_bounds__(256) void gemm128_f32(
    const bf16_t* __restrict__ A, const bf16_t* __restrict__ Bt,
    float* __restrict__ fout, int M, int N, int K)
{
  __shared__ bf16_t As[128 * 32];
  __shared__ bf16_t Bs[128 * 32];
  const int tid = threadIdx.x, wave = tid >> 6, lane = tid & 63;
  const int row0 = blockIdx.x * 128, col0 = blockIdx.y * 128;
  const int wr = wave >> 1, wc = wave & 1;
  f32x4 acc[4][4] = {};
  const int srow = lane >> 2, skoff = (lane & 3) * 8;
  const int nsteps = K >> 5;
  for (int kt = 0; kt < nsteps; ++kt) {
    const int k0 = kt << 5;
    #pragma unroll
    for (int i = 0; i < 2; ++i) {
      const int r = (i * 4 + wave) * 16 + srow;
      int arow = row0 + r; if (arow > M - 1) arow = M - 1;
      int brow = col0 + r; if (brow > N - 1) brow = N - 1;
      gload_lds16(A  + (size_t)arow * K + k0 + skoff, &As[r * 32 + skoff]);
      gload_lds16(Bt + (size_t)brow * K + k0 + skoff, &Bs[r * 32 + skoff]);
    }
    asm volatile("s_waitcnt vmcnt(0)" ::: "memory");
    __syncthreads();
    const int lrow = lane & 15, lk = (lane >> 4) * 8;
    bf16x8 af[4], bfr[4];
    #pragma unroll
    for (int mi = 0; mi < 4; ++mi)
      af[mi] = *(const bf16x8*)&As[(wr * 64 + mi * 16 + lrow) * 32 + lk];
    #pragma unroll
    for (int ni = 0; ni < 4; ++ni)
      bfr[ni] = *(const bf16x8*)&Bs[(wc * 64 + ni * 16 + lrow) * 32 + lk];
    #pragma unroll
    for (int mi = 0; mi < 4; ++mi)
      #pragma unroll
      for (int ni = 0; ni < 4; ++ni)
        acc[mi][ni] = __builtin_amdgcn_mfma_f32_16x16x32_bf16(af[mi], bfr[ni], acc[mi][ni], 0, 0, 0);
    __syncthreads();
  }
  const int lcol = lane & 15, rgrp = lane >> 4;
  #pragma unroll
  for (int mi = 0; mi < 4; ++mi)
    #pragma unroll
    for (int ni = 0; ni < 4; ++ni) {
      const int col = col0 + wc * 64 + ni * 16 + lcol;
      if (col >= N) continue;
      const int rbase = row0 + wr * 64 + mi * 16 + rgrp * 4;
      #pragma unroll
      for (int r = 0; r < 4; ++r) {
        const int rr = rbase + r;
        if (rr >= M) continue;
        fout[(size_t)rr * N + col] = acc[mi][ni][r];
      }
    }
}

// ---------------- LayerNorm: one wave per token, E=768 ----------------
__global__ __launch_bounds__(256) void ln_kernel(
    const float* __restrict__ t, const float* __restrict__ w,
    const float* __restrict__ b, bf16_t* __restrict__ y)
{
  const int token = blockIdx.x * 4 + (threadIdx.x >> 6);
  const int lane  = threadIdx.x & 63;
  const float* xp = t + (size_t)token * EDIM;
  float v[12];
  float s = 0.f;
  #pragma unroll
  for (int i = 0; i < 12; ++i) { v[i] = xp[lane + i * 64]; s += v[i]; }
  #pragma unroll
  for (int off = 32; off; off >>= 1) s += __shfl_xor(s, off);
  const float mu = s * (1.f / 768.f);
  float q = 0.f;
  #pragma unroll
  for (int i = 0; i < 12; ++i) { const float d = v[i] - mu; q += d * d; }
  #pragma unroll
  for (int off = 32; off; off >>= 1) q += __shfl_xor(q, off);
  const float rs = rsqrtf(q * (1.f / 768.f) + 1e-6f);
  bf16_t* yp = y + (size_t)token * EDIM;
  #pragma unroll
  for (int i = 0; i < 12; ++i) {
    const int e = lane + i * 64;
    yp[e] = (bf16_t)((v[i] - mu) * rs * w[e] + b[e]);
  }
}

// ---------------- row-wise attention: block per (b_local, s1, h) -----------
__global__ __launch_bounds__(256) void attn_kernel(
    const bf16_t* __restrict__ qkv, bf16_t* __restrict__ o)
{
  const int blk = blockIdx.x;
  const int h  = blk % 12;
  const int bs = blk / 12;
  const int s1 = bs % SDIM;
  const int b  = bs / SDIM;
  __shared__ float Qs[SDIM][65], Ks[SDIM][65], Vs[SDIM][65], Ps[SDIM][42];
  const int tid = threadIdx.x;
  const size_t base = ((size_t)b * LLEN + (size_t)s1 * SDIM);

  for (int idx = tid; idx < SDIM * 64; idx += 256) {
    const int m = idx >> 6, d = idx & 63;
    const bf16_t* p = qkv + (base + m) * 2304 + h * 64 + d;
    Qs[m][d] = (float)p[0];
    Ks[m][d] = (float)p[768];
    Vs[m][d] = (float)p[1536];
  }
  __syncthreads();

  for (int idx = tid; idx < SDIM * SDIM; idx += 256) {
    const int n = idx / SDIM, m = idx % SDIM;
    float s = 0.f;
    #pragma unroll
    for (int d = 0; d < 64; ++d) s += Qs[n][d] * Ks[m][d];
    Ps[n][m] = s * 0.125f;
  }
  __syncthreads();

  if (tid < SDIM) {
    float mx = -1e30f;
    for (int m = 0; m < SDIM; ++m) mx = fmaxf(mx, Ps[tid][m]);
    float sum = 0.f;
    for (int m = 0; m < SDIM; ++m) { const float e = __expf(Ps[tid][m] - mx); Ps[tid][m] = e; sum += e; }
    const float inv = 1.f / sum;
    for (int m = 0; m < SDIM; ++m) Ps[tid][m] *= inv;
  }
  __syncthreads();

  for (int idx = tid; idx < SDIM * 64; idx += 256) {
    const int n = idx >> 6, d = idx & 63;
    float s = 0.f;
    #pragma unroll
    for (int m = 0; m < SDIM; ++m) s += Ps[n][m] * Vs[m][d];
    o[(base + n) * EDIM + h * 64 + d] = (bf16_t)s;
  }
}

// ---------------- transpose fp32(KxN) -> bf16(NxK) ----------------
__global__ __launch_bounds__(256) void transpose_kernel(
    const float* __restrict__ in, bf16_t* __restrict__ out, int K, int N)
{
  __shared__ float tile[32][33];
  const int k0 = blockIdx.x * 32, n0 = blockIdx.y * 32;
  const int tx = threadIdx.x & 31, ty = threadIdx.x >> 5;
  #pragma unroll
  for (int i = 0; i < 32; i += 8) {
    const int k = k0 + ty + i, n = n0 + tx;
    if (k < K && n < N) tile[ty + i][tx] = in[(size_t)k * N + n];
  }
  __syncthreads();
  #pragma unroll
  for (int i = 0; i < 32; i += 8) {
    const int n = n0 + ty + i, k = k0 + tx;
    if (n < N && k < K) out[(size_t)n * K + k] = (bf16_t)tile[tx][ty + i];
  }
}

// ---------------- im2col for conv1 chunk (pad K 1200->1216) ----------------
__global__ __launch_bounds__(256) void im2col_kernel(
    const float* __restrict__ x, bf16_t* __restrict__ col, int tok0, int ntok)
{
  const size_t idx = (size_t)blockIdx.x * 256 + threadIdx.x;
  if (idx >= (size_t)ntok * 1216) return;
  const int kk = (int)(idx % 1216);
  const size_t tok = tok0 + idx / 1216;
  const int b = (int)(tok / LLEN), l = (int)(tok % LLEN);
  const int s1 = l / SDIM, s2 = l % SDIM;
  float v = 0.f;
  if (kk < 1200) {
    const int cin = kk / 100, r = kk % 100, ky = r / 10, kx = r % 10;
    const int iy = s1 - 5 + ky, ix = s2 - 5 + kx;
    if (iy >= 0 && iy < 40 && ix >= 0 && ix < 40)
      v = x[((size_t)(b * 12 + cin) * 40 + iy) * 40 + ix];
  }
  col[idx] = (bf16_t)v;
}

__global__ __launch_bounds__(256) void convw_kernel(
    const float* __restrict__ w, bf16_t* __restrict__ out)
{
  const int idx = blockIdx.x * 256 + threadIdx.x;
  const int kk = idx % 1216, e = idx / 1216;
  const float v = (kk < 1200) ? w[(size_t)e * 1200 + kk] : 0.f;
  out[idx] = (bf16_t)v;
}

__global__ __launch_bounds__(256) void tconvw_kernel(
    const float* __restrict__ w, bf16_t* __restrict__ out)
{
  const int idx = blockIdx.x * 256 + threadIdx.x;  // 100*768
  const int e = idx % 768, tap = idx / 768;
  const int ky = tap / 10, kx = tap % 10;
  out[idx] = (bf16_t)w[(size_t)e * 100 + (9 - ky) * 10 + (9 - kx)];
}

// ---------------- final gather ----------------
__global__ __launch_bounds__(256) void outconv_kernel(
    const float* __restrict__ g, const float* __restrict__ tb,
    float* __restrict__ out)
{
  const int idx = blockIdx.x * 256 + threadIdx.x;
  if (idx >= 16 * 40 * 40) return;
  const int x = idx % 40, y = (idx / 40) % 40, b = idx / 1600;
  float s = tb[0];
  #pragma unroll
  for (int ky = 0; ky < 10; ++ky) {
    const int ty_ = y - 4 + ky;
    if (ty_ < 0 || ty_ >= SDIM) continue;
    #pragma unroll
    for (int kx = 0; kx < 10; ++kx) {
      const int tx_ = x - 4 + kx;
      if (tx_ < 0 || tx_ >= SDIM) continue;
      s += g[((size_t)b * LLEN + ty_ * SDIM + tx_) * 100 + ky * 10 + kx];
    }
  }
  out[idx] = s;
}

// ============================================================================
extern "C" void kernel_launch(void* const* d_in, const int* in_sizes, int n_in,
                              void* d_out, int out_size, void* d_ws, size_t ws_size,
                              hipStream_t stream)
{
  const float* x       = (const float*)d_in[0];
  const float* conv_w  = (const float*)d_in[1];
  const float* conv_b  = (const float*)d_in[2];
  const float* pos     = (const float*)d_in[3];
  const float* ln1_w   = (const float*)d_in[4];
  const float* ln1_b   = (const float*)d_in[5];
  const float* qkv_w   = (const float*)d_in[6];
  const float* qkv_b   = (const float*)d_in[7];
  const float* proj_w  = (const float*)d_in[8];
  const float* proj_b  = (const float*)d_in[9];
  const float* ln2_w   = (const float*)d_in[10];
  const float* ln2_b   = (const float*)d_in[11];
  const float* fc1_w   = (const float*)d_in[12];
  const float* fc1_b   = (const float*)d_in[13];
  const float* fc2_w   = (const float*)d_in[14];
  const float* fc2_b   = (const float*)d_in[15];
  const float* lnf_w   = (const float*)d_in[16];
  const float* lnf_b   = (const float*)d_in[17];
  const float* tconv_w = (const float*)d_in[18];
  const float* tconv_b = (const float*)d_in[19];
  float* out = (float*)d_out;

  constexpr int LDS_N128 = 2 * (16384 + 128 * 64) * 2;   // 98304 B
  constexpr int LDS_N256 = 2 * (16384 + 256 * 64) * 2;   // 131072 B
  hipFuncSetAttribute((const void*)gemm5_kernel<128, EPI_T_POS>, hipFuncAttributeMaxDynamicSharedMemorySize, LDS_N128);
  hipFuncSetAttribute((const void*)gemm5_kernel<128, EPI_ADD_T>, hipFuncAttributeMaxDynamicSharedMemorySize, LDS_N128);
  hipFuncSetAttribute((const void*)gemm5_kernel<256, EPI_BF16 >, hipFuncAttributeMaxDynamicSharedMemorySize, LDS_N256);
  hipFuncSetAttribute((const void*)gemm5_kernel<256, EPI_GELU >, hipFuncAttributeMaxDynamicSharedMemorySize, LDS_N256);

  // ---- workspace tiers: nch=1 (303MB) > nch=2 (221MB) > nch=4 (179MB) ----
  const int nch = (ws_size >= 303500000UL) ? 1
                : (ws_size >= 220900000UL) ? 2 : 4;
  const int cht = TOKENS / nch;

  char* p = (char*)d_ws;
  auto alloc = [&](size_t bytes) {
    char* r = p;
    p += (bytes + 255) & ~(size_t)255;
    return r;
  };
  bf16_t* wbuf = (bf16_t*)alloc((size_t)768 * 9216 * 2);
  float*  t    = (float*)alloc((size_t)TOKENS * EDIM * 4);
  bf16_t* ybuf = (bf16_t*)alloc((size_t)TOKENS * EDIM * 2);
  bf16_t* hbuf = (bf16_t*)alloc((size_t)cht * 3072 * 2);

  bf16_t* Wq = wbuf;
  bf16_t* Wp = Wq + (size_t)2304 * 768;
  bf16_t* W1 = Wp + (size_t)768 * 768;
  bf16_t* W2 = W1 + (size_t)3072 * 768;

  auto g5 = [&](int bn, int epi, const bf16_t* A, const bf16_t* Bt,
                const float* bias, float* fo, bf16_t* bo, const float* pe,
                int M, int N, int K) {
    const int mtiles = (M + 255) / 256;
    const int ntn = N / bn;
    const int nwg = mtiles * ntn;
    if (bn == 128) {
      if (epi == EPI_T_POS)
        gemm5_kernel<128, EPI_T_POS><<<nwg, 512, LDS_N128, stream>>>(A, Bt, bias, fo, bo, pe, M, N, K, ntn, nwg);
      else
        gemm5_kernel<128, EPI_ADD_T><<<nwg, 512, LDS_N128, stream>>>(A, Bt, bias, fo, bo, pe, M, N, K, ntn, nwg);
    } else {
      if (epi == EPI_BF16)
        gemm5_kernel<256, EPI_BF16 ><<<nwg, 512, LDS_N256, stream>>>(A, Bt, bias, fo, bo, pe, M, N, K, ntn, nwg);
      else
        gemm5_kernel<256, EPI_GELU ><<<nwg, 512, LDS_N256, stream>>>(A, Bt, bias, fo, bo, pe, M, N, K, ntn, nwg);
    }
  };

  // ---- conv1 as chunked im2col GEMM -> t (+bias +pos_embed) ----
  convw_kernel<<<(768 * 1216) / 256, 256, 0, stream>>>(conv_w, wbuf);
  for (int c = 0; c < nch; ++c) {
    const int tok0 = c * cht;
    im2col_kernel<<<(unsigned)(((size_t)cht * 1216 + 255) / 256), 256, 0, stream>>>(x, hbuf, tok0, cht);
    g5(128, EPI_T_POS, hbuf, wbuf, conv_b, t + (size_t)tok0 * EDIM, nullptr, pos, cht, EDIM, 1216);
  }

  // ---- transformer layers ----
  for (int i = 0; i < 12; ++i) {
    transpose_kernel<<<dim3(24, 72), 256, 0, stream>>>(qkv_w + (size_t)i * 768 * 2304, Wq, 768, 2304);
    transpose_kernel<<<dim3(24, 24), 256, 0, stream>>>(proj_w + (size_t)i * 768 * 768, Wp, 768, 768);
    transpose_kernel<<<dim3(24, 96), 256, 0, stream>>>(fc1_w + (size_t)i * 768 * 3072, W1, 768, 3072);
    transpose_kernel<<<dim3(96, 24), 256, 0, stream>>>(fc2_w + (size_t)i * 3072 * 768, W2, 3072, 768);

    ln_kernel<<<TOKENS / 4, 256, 0, stream>>>(t, ln1_w + i * EDIM, ln1_b + i * EDIM, ybuf);
    for (int c = 0; c < nch; ++c) {
      const size_t ro = (size_t)c * cht;
      g5(256, EPI_BF16, ybuf + ro * EDIM, Wq, qkv_b + i * 2304, nullptr, hbuf, nullptr, cht, 2304, 768);
      attn_kernel<<<(16 / nch) * SDIM * 12, 256, 0, stream>>>(hbuf, ybuf + ro * EDIM);
    }
    g5(128, EPI_ADD_T, ybuf, Wp, proj_b + i * EDIM, t, nullptr, nullptr, TOKENS, EDIM, 768);

    ln_kernel<<<TOKENS / 4, 256, 0, stream>>>(t, ln2_w + i * EDIM, ln2_b + i * EDIM, ybuf);
    for (int c = 0; c < nch; ++c) {
      const size_t ro = (size_t)c * cht;
      g5(256, EPI_GELU, ybuf + ro * EDIM, W1, fc1_b + i * 3072, nullptr, hbuf, nullptr, cht, 3072, 768);
      g5(128, EPI_ADD_T, hbuf, W2, fc2_b + i * EDIM, t + ro * EDIM, nullptr, nullptr, cht, EDIM, 3072);
    }
  }

  // ---- final LN + tconv head ----
  ln_kernel<<<TOKENS / 4, 256, 0, stream>>>(t, lnf_w, lnf_b, ybuf);
  tconvw_kernel<<<(100 * 768) / 256, 256, 0, stream>>>(tconv_w, wbuf);
  gemm128_f32<<<dim3((TOKENS + 127) / 128, 1), 256, 0, stream>>>(ybuf, wbuf, (float*)hbuf, TOKENS, 100, 768);
  outconv_kernel<<<100, 256, 0, stream>>>((const float*)hbuf, tconv_b, out);
}

// Round 8
// 10937.508 us; speedup vs baseline: 1.2733x; 1.1204x over previous
//
#include <hip/hip_runtime.h>
#include <cstdint>

typedef __bf16 bf16_t;
typedef __attribute__((ext_vector_type(8))) __bf16 bf16x8;
typedef __attribute__((ext_vector_type(4))) __bf16 bf16x4;
typedef __attribute__((ext_vector_type(4))) float f32x4;

#define TOKENS 26896
#define LLEN   1681
#define SDIM   41
#define EDIM   768

// ---------------- async global->LDS 16B ----------------
__device__ __forceinline__ void gload_lds16(const bf16_t* g, bf16_t* l) {
  auto gp = reinterpret_cast<const __attribute__((address_space(1))) char*>(
      reinterpret_cast<uintptr_t>(g));
  auto lp = reinterpret_cast<__attribute__((address_space(3))) char*>(
      reinterpret_cast<uintptr_t>(l));
  __builtin_amdgcn_global_load_lds(gp, lp, 16, 0, 0);
}

enum { EPI_T_POS = 0, EPI_BF16 = 1, EPI_ADD_T = 2, EPI_GELU = 3, EPI_F32 = 4 };

// ============================================================================
// gemm4 (R5-proven): C = A(MxK,bf16) @ Bt(NxK,bf16)^T
// 128x128 tile, BK=32, 256 thr (2x2 waves, 64x64/wave), ring-2 in 32KB static
// LDS -> 4 blocks/CU (16 waves/CU; cross-block overlap hides barrier drains).
// Row-major tile order + bijective XCD swizzle. XOR-swizzled LDS (0 conflicts
// measured). Frag reads: base + compile-time immediates.
// ============================================================================
template <int EPI>
__global__ __launch_bounds__(256, 4) void gemm4_kernel(
    const bf16_t* __restrict__ A, const bf16_t* __restrict__ Bt,
    const float* __restrict__ bias, float* __restrict__ fout,
    bf16_t* __restrict__ bout, const float* __restrict__ pos,
    int M, int N, int K, int ntn, int nwg)
{
  __shared__ bf16_t lds[16384];      // [2 bufs][A:128x32][B:128x32]
  const int tid = threadIdx.x, wave = tid >> 6, lane = tid & 63;
  const int wr = wave >> 1, wc = wave & 1;

  int id = blockIdx.x;
  {
    const int q = nwg >> 3, r = nwg & 7;
    const int xcd = id & 7, ix = id >> 3;
    id = (xcd < r ? xcd * (q + 1) : r * (q + 1) + (xcd - r) * q) + ix;
  }
  const int row0 = (id / ntn) * 128;
  const int col0 = (id % ntn) * 128;
  const int NT = K >> 5;

  const int srow = tid >> 2;                                  // 0..63
  const int sswz = ((tid & 3) ^ ((srow >> 1) & 3)) * 8;       // inv-swz src col
  const bf16_t* aptr[2];
  const bf16_t* bptr[2];
  #pragma unroll
  for (int p = 0; p < 2; ++p) {
    int ar = row0 + p * 64 + srow; if (ar > M - 1) ar = M - 1;
    int br = col0 + p * 64 + srow; if (br > N - 1) br = N - 1;
    aptr[p] = A  + (size_t)ar * K + sswz;
    bptr[p] = Bt + (size_t)br * K + sswz;
  }
  bf16_t* sdst = lds + tid * 8;

  #define STAGE(BUF, KT) do {                                   \
    const int koff_ = (KT) << 5;                                \
    gload_lds16(aptr[0] + koff_, sdst + (BUF)*8192);            \
    gload_lds16(aptr[1] + koff_, sdst + (BUF)*8192 + 2048);     \
    gload_lds16(bptr[0] + koff_, sdst + (BUF)*8192 + 4096);     \
    gload_lds16(bptr[1] + koff_, sdst + (BUF)*8192 + 6144);     \
  } while (0)

  const int l15 = lane & 15, l4 = lane >> 4;
  const int fswz = (l4 ^ ((l15 >> 1) & 3)) << 3;
  const bf16_t* lA = lds + (wr * 64 + l15) * 32 + fswz;
  const bf16_t* lB = lds + 4096 + (wc * 64 + l15) * 32 + fswz;

  f32x4 acc[4][4] = {};

  #define COMPUTE(BUF) do {                                     \
    bf16x8 fa[4], fb[4];                                        \
    _Pragma("unroll")                                           \
    for (int m_ = 0; m_ < 4; ++m_) fa[m_] = *(const bf16x8*)(lA + (BUF)*8192 + m_*512); \
    _Pragma("unroll")                                           \
    for (int n_ = 0; n_ < 4; ++n_) fb[n_] = *(const bf16x8*)(lB + (BUF)*8192 + n_*512); \
    _Pragma("unroll")                                           \
    for (int m_ = 0; m_ < 4; ++m_)                              \
      _Pragma("unroll")                                         \
      for (int n_ = 0; n_ < 4; ++n_)                            \
        acc[m_][n_] = __builtin_amdgcn_mfma_f32_16x16x32_bf16(fa[m_], fb[n_], acc[m_][n_], 0, 0, 0); \
  } while (0)

  STAGE(0, 0);
  __syncthreads();
  int kt = 0;
  while (kt + 2 <= NT) {
    if (kt + 1 < NT) STAGE(1, kt + 1);
    COMPUTE(0);
    __syncthreads();
    if (kt + 2 < NT) STAGE(0, kt + 2);
    COMPUTE(1);
    __syncthreads();
    kt += 2;
  }
  if (kt < NT) COMPUTE(0);
  #undef STAGE
  #undef COMPUTE

  const int rgrp = lane >> 4;
  #pragma unroll
  for (int m = 0; m < 4; ++m) {
    #pragma unroll
    for (int n = 0; n < 4; ++n) {
      const int col = col0 + wc * 64 + n * 16 + l15;
      if (col >= N) continue;
      const int rbase = row0 + wr * 64 + m * 16 + rgrp * 4;
      float bv = 0.f;
      if constexpr (EPI != EPI_F32) bv = bias[col];
      #pragma unroll
      for (int r = 0; r < 4; ++r) {
        const int rr = rbase + r;
        if (rr >= M) continue;
        const float v = acc[m][n][r] + bv;
        const size_t o = (size_t)rr * N + col;
        if constexpr (EPI == EPI_T_POS) {
          const int l = rr % LLEN;
          fout[o] = v + pos[(size_t)l * N + col];
        } else if constexpr (EPI == EPI_BF16) {
          bout[o] = (bf16_t)v;
        } else if constexpr (EPI == EPI_ADD_T) {
          fout[o] += v;
        } else if constexpr (EPI == EPI_GELU) {
          const float gg = 0.5f * v * (1.f + erff(v * 0.70710678118654752f));
          bout[o] = (bf16_t)gg;
        } else {
          fout[o] = v;
        }
      }
    }
  }
}

// ---------------- head GEMM (N=100), simple 128x128 ----------------
__global__ __launch_bounds__(256) void gemm128_f32(
    const bf16_t* __restrict__ A, const bf16_t* __restrict__ Bt,
    float* __restrict__ fout, int M, int N, int K)
{
  __shared__ bf16_t As[128 * 32];
  __shared__ bf16_t Bs[128 * 32];
  const int tid = threadIdx.x, wave = tid >> 6, lane = tid & 63;
  const int row0 = blockIdx.x * 128, col0 = blockIdx.y * 128;
  const int wr = wave >> 1, wc = wave & 1;
  f32x4 acc[4][4] = {};
  const int srow = lane >> 2, skoff = (lane & 3) * 8;
  const int nsteps = K >> 5;
  for (int kt = 0; kt < nsteps; ++kt) {
    const int k0 = kt << 5;
    #pragma unroll
    for (int i = 0; i < 2; ++i) {
      const int r = (i * 4 + wave) * 16 + srow;
      int arow = row0 + r; if (arow > M - 1) arow = M - 1;
      int brow = col0 + r; if (brow > N - 1) brow = N - 1;
      gload_lds16(A  + (size_t)arow * K + k0 + skoff, &As[r * 32 + skoff]);
      gload_lds16(Bt + (size_t)brow * K + k0 + skoff, &Bs[r * 32 + skoff]);
    }
    asm volatile("s_waitcnt vmcnt(0)" ::: "memory");
    __syncthreads();
    const int lrow = lane & 15, lk = (lane >> 4) * 8;
    bf16x8 af[4], bfr[4];
    #pragma unroll
    for (int mi = 0; mi < 4; ++mi)
      af[mi] = *(const bf16x8*)&As[(wr * 64 + mi * 16 + lrow) * 32 + lk];
    #pragma unroll
    for (int ni = 0; ni < 4; ++ni)
      bfr[ni] = *(const bf16x8*)&Bs[(wc * 64 + ni * 16 + lrow) * 32 + lk];
    #pragma unroll
    for (int mi = 0; mi < 4; ++mi)
      #pragma unroll
      for (int ni = 0; ni < 4; ++ni)
        acc[mi][ni] = __builtin_amdgcn_mfma_f32_16x16x32_bf16(af[mi], bfr[ni], acc[mi][ni], 0, 0, 0);
    __syncthreads();
  }
  const int lcol = lane & 15, rgrp = lane >> 4;
  #pragma unroll
  for (int mi = 0; mi < 4; ++mi)
    #pragma unroll
    for (int ni = 0; ni < 4; ++ni) {
      const int col = col0 + wc * 64 + ni * 16 + lcol;
      if (col >= N) continue;
      const int rbase = row0 + wr * 64 + mi * 16 + rgrp * 4;
      #pragma unroll
      for (int r = 0; r < 4; ++r) {
        const int rr = rbase + r;
        if (rr >= M) continue;
        fout[(size_t)rr * N + col] = acc[mi][ni][r];
      }
    }
}

// ---------------- LayerNorm: one wave per token, float4 loads ----------------
__global__ __launch_bounds__(256) void ln_kernel(
    const float* __restrict__ t, const float* __restrict__ w,
    const float* __restrict__ b, bf16_t* __restrict__ y)
{
  const int token = blockIdx.x * 4 + (threadIdx.x >> 6);
  const int lane  = threadIdx.x & 63;
  const float4* xp = (const float4*)(t + (size_t)token * EDIM);
  float4 v[3];
  float s = 0.f;
  #pragma unroll
  for (int i = 0; i < 3; ++i) {
    v[i] = xp[i * 64 + lane];
    s += v[i].x + v[i].y + v[i].z + v[i].w;
  }
  #pragma unroll
  for (int off = 32; off; off >>= 1) s += __shfl_xor(s, off);
  const float mu = s * (1.f / 768.f);
  float q = 0.f;
  #pragma unroll
  for (int i = 0; i < 3; ++i) {
    const float dx = v[i].x - mu, dy = v[i].y - mu;
    const float dz = v[i].z - mu, dw = v[i].w - mu;
    q += dx * dx + dy * dy + dz * dz + dw * dw;
  }
  #pragma unroll
  for (int off = 32; off; off >>= 1) q += __shfl_xor(q, off);
  const float rs = rsqrtf(q * (1.f / 768.f) + 1e-6f);
  bf16_t* yp = y + (size_t)token * EDIM;
  #pragma unroll
  for (int i = 0; i < 3; ++i) {
    const int e = i * 64 + lane;
    const float4 wv = ((const float4*)w)[e];
    const float4 bv = ((const float4*)b)[e];
    bf16x4 o;
    o[0] = (bf16_t)((v[i].x - mu) * rs * wv.x + bv.x);
    o[1] = (bf16_t)((v[i].y - mu) * rs * wv.y + bv.y);
    o[2] = (bf16_t)((v[i].z - mu) * rs * wv.z + bv.z);
    o[3] = (bf16_t)((v[i].w - mu) * rs * wv.w + bv.w);
    *(bf16x4*)(yp + e * 4) = o;
  }
}

// ---------------- row-wise attention: block per (b_local, s1, h) -----------
// bf16x8 vectorized loads; wave-parallel softmax (4 lanes per row).
__global__ __launch_bounds__(256) void attn_kernel(
    const bf16_t* __restrict__ qkv, bf16_t* __restrict__ o)
{
  const int blk = blockIdx.x;
  const int h  = blk % 12;
  const int bs = blk / 12;
  const int s1 = bs % SDIM;
  const int b  = bs / SDIM;
  __shared__ float Qs[SDIM][65], Ks[SDIM][65], Vs[SDIM][65], Ps[SDIM][44];
  const int tid = threadIdx.x;
  const size_t base = ((size_t)b * LLEN + (size_t)s1 * SDIM);

  // vectorized load: 41 rows x 8 chunks of 8 bf16
  for (int idx = tid; idx < SDIM * 8; idx += 256) {
    const int m = idx >> 3, c = idx & 7;
    const bf16_t* p = qkv + (base + m) * 2304 + h * 64 + c * 8;
    const bf16x8 qv = *(const bf16x8*)(p);
    const bf16x8 kv = *(const bf16x8*)(p + 768);
    const bf16x8 vv = *(const bf16x8*)(p + 1536);
    #pragma unroll
    for (int j = 0; j < 8; ++j) {
      Qs[m][c * 8 + j] = (float)qv[j];
      Ks[m][c * 8 + j] = (float)kv[j];
      Vs[m][c * 8 + j] = (float)vv[j];
    }
  }
  __syncthreads();

  for (int idx = tid; idx < SDIM * SDIM; idx += 256) {
    const int n = idx / SDIM, m = idx % SDIM;
    float s = 0.f;
    #pragma unroll
    for (int d = 0; d < 64; ++d) s += Qs[n][d] * Ks[m][d];
    Ps[n][m] = s * 0.125f;
  }
  __syncthreads();

  // wave-parallel softmax: 4 lanes per row
  {
    const int row = tid >> 2, sub = tid & 3;
    if (row < SDIM) {
      float mx = -1e30f;
      for (int m = sub; m < SDIM; m += 4) mx = fmaxf(mx, Ps[row][m]);
      mx = fmaxf(mx, __shfl_xor(mx, 1));
      mx = fmaxf(mx, __shfl_xor(mx, 2));
      float sum = 0.f;
      for (int m = sub; m < SDIM; m += 4) {
        const float e = __expf(Ps[row][m] - mx);
        Ps[row][m] = e;
        sum += e;
      }
      sum += __shfl_xor(sum, 1);
      sum += __shfl_xor(sum, 2);
      const float inv = 1.f / sum;
      for (int m = sub; m < SDIM; m += 4) Ps[row][m] *= inv;
    }
  }
  __syncthreads();

  for (int idx = tid; idx < SDIM * 64; idx += 256) {
    const int n = idx >> 6, d = idx & 63;
    float s = 0.f;
    #pragma unroll
    for (int m = 0; m < SDIM; ++m) s += Ps[n][m] * Vs[m][d];
    o[(base + n) * EDIM + h * 64 + d] = (bf16_t)s;
  }
}

// ---------------- transpose fp32(KxN) -> bf16(NxK) ----------------
__global__ __launch_bounds__(256) void transpose_kernel(
    const float* __restrict__ in, bf16_t* __restrict__ out, int K, int N)
{
  __shared__ float tile[32][33];
  const int k0 = blockIdx.x * 32, n0 = blockIdx.y * 32;
  const int tx = threadIdx.x & 31, ty = threadIdx.x >> 5;
  #pragma unroll
  for (int i = 0; i < 32; i += 8) {
    const int k = k0 + ty + i, n = n0 + tx;
    if (k < K && n < N) tile[ty + i][tx] = in[(size_t)k * N + n];
  }
  __syncthreads();
  #pragma unroll
  for (int i = 0; i < 32; i += 8) {
    const int n = n0 + ty + i, k = k0 + tx;
    if (n < N && k < K) out[(size_t)n * K + k] = (bf16_t)tile[tx][ty + i];
  }
}

// ---------------- im2col for conv1 chunk (pad K 1200->1216) ----------------
__global__ __launch_bounds__(256) void im2col_kernel(
    const float* __restrict__ x, bf16_t* __restrict__ col, int tok0, int ntok)
{
  const size_t idx = (size_t)blockIdx.x * 256 + threadIdx.x;
  if (idx >= (size_t)ntok * 1216) return;
  const int kk = (int)(idx % 1216);
  const size_t tok = tok0 + idx / 1216;
  const int b = (int)(tok / LLEN), l = (int)(tok % LLEN);
  const int s1 = l / SDIM, s2 = l % SDIM;
  float v = 0.f;
  if (kk < 1200) {
    const int cin = kk / 100, r = kk % 100, ky = r / 10, kx = r % 10;
    const int iy = s1 - 5 + ky, ix = s2 - 5 + kx;
    if (iy >= 0 && iy < 40 && ix >= 0 && ix < 40)
      v = x[((size_t)(b * 12 + cin) * 40 + iy) * 40 + ix];
  }
  col[idx] = (bf16_t)v;
}

__global__ __launch_bounds__(256) void convw_kernel(
    const float* __restrict__ w, bf16_t* __restrict__ out)
{
  const int idx = blockIdx.x * 256 + threadIdx.x;
  const int kk = idx % 1216, e = idx / 1216;
  const float v = (kk < 1200) ? w[(size_t)e * 1200 + kk] : 0.f;
  out[idx] = (bf16_t)v;
}

__global__ __launch_bounds__(256) void tconvw_kernel(
    const float* __restrict__ w, bf16_t* __restrict__ out)
{
  const int idx = blockIdx.x * 256 + threadIdx.x;  // 100*768
  const int e = idx % 768, tap = idx / 768;
  const int ky = tap / 10, kx = tap % 10;
  out[idx] = (bf16_t)w[(size_t)e * 100 + (9 - ky) * 10 + (9 - kx)];
}

// ---------------- final gather ----------------
__global__ __launch_bounds__(256) void outconv_kernel(
    const float* __restrict__ g, const float* __restrict__ tb,
    float* __restrict__ out)
{
  const int idx = blockIdx.x * 256 + threadIdx.x;
  if (idx >= 16 * 40 * 40) return;
  const int x = idx % 40, y = (idx / 40) % 40, b = idx / 1600;
  float s = tb[0];
  #pragma unroll
  for (int ky = 0; ky < 10; ++ky) {
    const int ty_ = y - 4 + ky;
    if (ty_ < 0 || ty_ >= SDIM) continue;
    #pragma unroll
    for (int kx = 0; kx < 10; ++kx) {
      const int tx_ = x - 4 + kx;
      if (tx_ < 0 || tx_ >= SDIM) continue;
      s += g[((size_t)b * LLEN + ty_ * SDIM + tx_) * 100 + ky * 10 + kx];
    }
  }
  out[idx] = s;
}

// ============================================================================
extern "C" void kernel_launch(void* const* d_in, const int* in_sizes, int n_in,
                              void* d_out, int out_size, void* d_ws, size_t ws_size,
                              hipStream_t stream)
{
  const float* x       = (const float*)d_in[0];
  const float* conv_w  = (const float*)d_in[1];
  const float* conv_b  = (const float*)d_in[2];
  const float* pos     = (const float*)d_in[3];
  const float* ln1_w   = (const float*)d_in[4];
  const float* ln1_b   = (const float*)d_in[5];
  const float* qkv_w   = (const float*)d_in[6];
  const float* qkv_b   = (const float*)d_in[7];
  const float* proj_w  = (const float*)d_in[8];
  const float* proj_b  = (const float*)d_in[9];
  const float* ln2_w   = (const float*)d_in[10];
  const float* ln2_b   = (const float*)d_in[11];
  const float* fc1_w   = (const float*)d_in[12];
  const float* fc1_b   = (const float*)d_in[13];
  const float* fc2_w   = (const float*)d_in[14];
  const float* fc2_b   = (const float*)d_in[15];
  const float* lnf_w   = (const float*)d_in[16];
  const float* lnf_b   = (const float*)d_in[17];
  const float* tconv_w = (const float*)d_in[18];
  const float* tconv_b = (const float*)d_in[19];
  float* out = (float*)d_out;

  // ---- workspace tiers: nch=1 (303MB) > nch=2 (221MB) > nch=4 (179MB) ----
  const int nch = (ws_size >= 303500000UL) ? 1
                : (ws_size >= 220900000UL) ? 2 : 4;
  const int cht = TOKENS / nch;

  char* p = (char*)d_ws;
  auto alloc = [&](size_t bytes) {
    char* r = p;
    p += (bytes + 255) & ~(size_t)255;
    return r;
  };
  bf16_t* wbuf = (bf16_t*)alloc((size_t)768 * 9216 * 2);
  float*  t    = (float*)alloc((size_t)TOKENS * EDIM * 4);
  bf16_t* ybuf = (bf16_t*)alloc((size_t)TOKENS * EDIM * 2);
  bf16_t* hbuf = (bf16_t*)alloc((size_t)cht * 3072 * 2);

  bf16_t* Wq = wbuf;
  bf16_t* Wp = Wq + (size_t)2304 * 768;
  bf16_t* W1 = Wp + (size_t)768 * 768;
  bf16_t* W2 = W1 + (size_t)3072 * 768;

  auto g4 = [&](int epi, const bf16_t* A, const bf16_t* Bt,
                const float* bias, float* fo, bf16_t* bo, const float* pe,
                int M, int N, int K) {
    const int mtiles = (M + 127) / 128;
    const int ntn = N / 128;
    const int nwg = mtiles * ntn;
    switch (epi) {
      case EPI_T_POS: gemm4_kernel<EPI_T_POS><<<nwg, 256, 0, stream>>>(A, Bt, bias, fo, bo, pe, M, N, K, ntn, nwg); break;
      case EPI_BF16:  gemm4_kernel<EPI_BF16 ><<<nwg, 256, 0, stream>>>(A, Bt, bias, fo, bo, pe, M, N, K, ntn, nwg); break;
      case EPI_ADD_T: gemm4_kernel<EPI_ADD_T><<<nwg, 256, 0, stream>>>(A, Bt, bias, fo, bo, pe, M, N, K, ntn, nwg); break;
      default:        gemm4_kernel<EPI_GELU ><<<nwg, 256, 0, stream>>>(A, Bt, bias, fo, bo, pe, M, N, K, ntn, nwg); break;
    }
  };

  // ---- conv1 as chunked im2col GEMM -> t (+bias +pos_embed) ----
  convw_kernel<<<(768 * 1216) / 256, 256, 0, stream>>>(conv_w, wbuf);
  for (int c = 0; c < nch; ++c) {
    const int tok0 = c * cht;
    im2col_kernel<<<(unsigned)(((size_t)cht * 1216 + 255) / 256), 256, 0, stream>>>(x, hbuf, tok0, cht);
    g4(EPI_T_POS, hbuf, wbuf, conv_b, t + (size_t)tok0 * EDIM, nullptr, pos, cht, EDIM, 1216);
  }

  // ---- transformer layers ----
  for (int i = 0; i < 12; ++i) {
    transpose_kernel<<<dim3(24, 72), 256, 0, stream>>>(qkv_w + (size_t)i * 768 * 2304, Wq, 768, 2304);
    transpose_kernel<<<dim3(24, 24), 256, 0, stream>>>(proj_w + (size_t)i * 768 * 768, Wp, 768, 768);
    transpose_kernel<<<dim3(24, 96), 256, 0, stream>>>(fc1_w + (size_t)i * 768 * 3072, W1, 768, 3072);
    transpose_kernel<<<dim3(96, 24), 256, 0, stream>>>(fc2_w + (size_t)i * 3072 * 768, W2, 3072, 768);

    ln_kernel<<<TOKENS / 4, 256, 0, stream>>>(t, ln1_w + i * EDIM, ln1_b + i * EDIM, ybuf);
    for (int c = 0; c < nch; ++c) {
      const size_t ro = (size_t)c * cht;
      g4(EPI_BF16, ybuf + ro * EDIM, Wq, qkv_b + i * 2304, nullptr, hbuf, nullptr, cht, 2304, 768);
      attn_kernel<<<(16 / nch) * SDIM * 12, 256, 0, stream>>>(hbuf, ybuf + ro * EDIM);
    }
    g4(EPI_ADD_T, ybuf, Wp, proj_b + i * EDIM, t, nullptr, nullptr, TOKENS, EDIM, 768);

    ln_kernel<<<TOKENS / 4, 256, 0, stream>>>(t, ln2_w + i * EDIM, ln2_b + i * EDIM, ybuf);
    for (int c = 0; c < nch; ++c) {
      const size_t ro = (size_t)c * cht;
      g4(EPI_GELU, ybuf + ro * EDIM, W1, fc1_b + i * 3072, nullptr, hbuf, nullptr, cht, 3072, 768);
      g4(EPI_ADD_T, hbuf, W2, fc2_b + i * EDIM, t + ro * EDIM, nullptr, nullptr, cht, EDIM, 3072);
    }
  }

  // ---- final LN + tconv head ----
  ln_kernel<<<TOKENS / 4, 256, 0, stream>>>(t, lnf_w, lnf_b, ybuf);
  tconvw_kernel<<<(100 * 768) / 256, 256, 0, stream>>>(tconv_w, wbuf);
  gemm128_f32<<<dim3((TOKENS + 127) / 128, 1), 256, 0, stream>>>(ybuf, wbuf, (float*)hbuf, TOKENS, 100, 768);
  outconv_kernel<<<100, 256, 0, stream>>>((const float*)hbuf, tconv_b, out);
}

// Round 9
// 10202.654 us; speedup vs baseline: 1.3650x; 1.0720x over previous
//
#include <hip/hip_runtime.h>
#include <cstdint>

typedef __bf16 bf16_t;
typedef __attribute__((ext_vector_type(8))) __bf16 bf16x8;
typedef __attribute__((ext_vector_type(4))) __bf16 bf16x4;
typedef __attribute__((ext_vector_type(4))) float f32x4;

#define TOKENS 26896
#define LLEN   1681
#define SDIM   41
#define EDIM   768

// ---------------- async global->LDS 16B ----------------
__device__ __forceinline__ void gload_lds16(const bf16_t* g, bf16_t* l) {
  auto gp = reinterpret_cast<const __attribute__((address_space(1))) char*>(
      reinterpret_cast<uintptr_t>(g));
  auto lp = reinterpret_cast<__attribute__((address_space(3))) char*>(
      reinterpret_cast<uintptr_t>(l));
  __builtin_amdgcn_global_load_lds(gp, lp, 16, 0, 0);
}

enum { EPI_T_POS = 0, EPI_BF16 = 1, EPI_ADD_T = 2, EPI_GELU = 3, EPI_F32 = 4 };

// ============================================================================
// gemm4 (R5/R8-proven): C = A(MxK,bf16) @ Bt(NxK,bf16)^T
// 128x128 tile, BK=32, 256 thr, ring-2 in 32KB static LDS -> 4 blocks/CU.
// Row-major tile order + bijective XCD swizzle; XOR-swizzled LDS (0 conflicts
// measured). t-residual epilogues now bf16 (R9: traffic halving).
// ============================================================================
template <int EPI>
__global__ __launch_bounds__(256, 4) void gemm4_kernel(
    const bf16_t* __restrict__ A, const bf16_t* __restrict__ Bt,
    const float* __restrict__ bias, float* __restrict__ fout,
    bf16_t* __restrict__ bout, const float* __restrict__ pos,
    int M, int N, int K, int ntn, int nwg)
{
  __shared__ bf16_t lds[16384];      // [2 bufs][A:128x32][B:128x32]
  const int tid = threadIdx.x, wave = tid >> 6, lane = tid & 63;
  const int wr = wave >> 1, wc = wave & 1;

  int id = blockIdx.x;
  {
    const int q = nwg >> 3, r = nwg & 7;
    const int xcd = id & 7, ix = id >> 3;
    id = (xcd < r ? xcd * (q + 1) : r * (q + 1) + (xcd - r) * q) + ix;
  }
  const int row0 = (id / ntn) * 128;
  const int col0 = (id % ntn) * 128;
  const int NT = K >> 5;

  const int srow = tid >> 2;                                  // 0..63
  const int sswz = ((tid & 3) ^ ((srow >> 1) & 3)) * 8;       // inv-swz src col
  const bf16_t* aptr[2];
  const bf16_t* bptr[2];
  #pragma unroll
  for (int p = 0; p < 2; ++p) {
    int ar = row0 + p * 64 + srow; if (ar > M - 1) ar = M - 1;
    int br = col0 + p * 64 + srow; if (br > N - 1) br = N - 1;
    aptr[p] = A  + (size_t)ar * K + sswz;
    bptr[p] = Bt + (size_t)br * K + sswz;
  }
  bf16_t* sdst = lds + tid * 8;

  #define STAGE(BUF, KT) do {                                   \
    const int koff_ = (KT) << 5;                                \
    gload_lds16(aptr[0] + koff_, sdst + (BUF)*8192);            \
    gload_lds16(aptr[1] + koff_, sdst + (BUF)*8192 + 2048);     \
    gload_lds16(bptr[0] + koff_, sdst + (BUF)*8192 + 4096);     \
    gload_lds16(bptr[1] + koff_, sdst + (BUF)*8192 + 6144);     \
  } while (0)

  const int l15 = lane & 15, l4 = lane >> 4;
  const int fswz = (l4 ^ ((l15 >> 1) & 3)) << 3;
  const bf16_t* lA = lds + (wr * 64 + l15) * 32 + fswz;
  const bf16_t* lB = lds + 4096 + (wc * 64 + l15) * 32 + fswz;

  f32x4 acc[4][4] = {};

  #define COMPUTE(BUF) do {                                     \
    bf16x8 fa[4], fb[4];                                        \
    _Pragma("unroll")                                           \
    for (int m_ = 0; m_ < 4; ++m_) fa[m_] = *(const bf16x8*)(lA + (BUF)*8192 + m_*512); \
    _Pragma("unroll")                                           \
    for (int n_ = 0; n_ < 4; ++n_) fb[n_] = *(const bf16x8*)(lB + (BUF)*8192 + n_*512); \
    _Pragma("unroll")                                           \
    for (int m_ = 0; m_ < 4; ++m_)                              \
      _Pragma("unroll")                                         \
      for (int n_ = 0; n_ < 4; ++n_)                            \
        acc[m_][n_] = __builtin_amdgcn_mfma_f32_16x16x32_bf16(fa[m_], fb[n_], acc[m_][n_], 0, 0, 0); \
  } while (0)

  STAGE(0, 0);
  __syncthreads();
  int kt = 0;
  while (kt + 2 <= NT) {
    if (kt + 1 < NT) STAGE(1, kt + 1);
    COMPUTE(0);
    __syncthreads();
    if (kt + 2 < NT) STAGE(0, kt + 2);
    COMPUTE(1);
    __syncthreads();
    kt += 2;
  }
  if (kt < NT) COMPUTE(0);
  #undef STAGE
  #undef COMPUTE

  const int rgrp = lane >> 4;
  #pragma unroll
  for (int m = 0; m < 4; ++m) {
    #pragma unroll
    for (int n = 0; n < 4; ++n) {
      const int col = col0 + wc * 64 + n * 16 + l15;
      if (col >= N) continue;
      const int rbase = row0 + wr * 64 + m * 16 + rgrp * 4;
      float bv = 0.f;
      if constexpr (EPI != EPI_F32) bv = bias[col];
      #pragma unroll
      for (int r = 0; r < 4; ++r) {
        const int rr = rbase + r;
        if (rr >= M) continue;
        const float v = acc[m][n][r] + bv;
        const size_t o = (size_t)rr * N + col;
        if constexpr (EPI == EPI_T_POS) {
          const int l = rr % LLEN;
          bout[o] = (bf16_t)(v + pos[(size_t)l * N + col]);
        } else if constexpr (EPI == EPI_BF16) {
          bout[o] = (bf16_t)v;
        } else if constexpr (EPI == EPI_ADD_T) {
          bout[o] = (bf16_t)((float)bout[o] + v);
        } else if constexpr (EPI == EPI_GELU) {
          const float gg = 0.5f * v * (1.f + erff(v * 0.70710678118654752f));
          bout[o] = (bf16_t)gg;
        } else {
          fout[o] = v;
        }
      }
    }
  }
}

// ---------------- head GEMM (N=100), simple 128x128 ----------------
__global__ __launch_bounds__(256) void gemm128_f32(
    const bf16_t* __restrict__ A, const bf16_t* __restrict__ Bt,
    float* __restrict__ fout, int M, int N, int K)
{
  __shared__ bf16_t As[128 * 32];
  __shared__ bf16_t Bs[128 * 32];
  const int tid = threadIdx.x, wave = tid >> 6, lane = tid & 63;
  const int row0 = blockIdx.x * 128, col0 = blockIdx.y * 128;
  const int wr = wave >> 1, wc = wave & 1;
  f32x4 acc[4][4] = {};
  const int srow = lane >> 2, skoff = (lane & 3) * 8;
  const int nsteps = K >> 5;
  for (int kt = 0; kt < nsteps; ++kt) {
    const int k0 = kt << 5;
    #pragma unroll
    for (int i = 0; i < 2; ++i) {
      const int r = (i * 4 + wave) * 16 + srow;
      int arow = row0 + r; if (arow > M - 1) arow = M - 1;
      int brow = col0 + r; if (brow > N - 1) brow = N - 1;
      gload_lds16(A  + (size_t)arow * K + k0 + skoff, &As[r * 32 + skoff]);
      gload_lds16(Bt + (size_t)brow * K + k0 + skoff, &Bs[r * 32 + skoff]);
    }
    asm volatile("s_waitcnt vmcnt(0)" ::: "memory");
    __syncthreads();
    const int lrow = lane & 15, lk = (lane >> 4) * 8;
    bf16x8 af[4], bfr[4];
    #pragma unroll
    for (int mi = 0; mi < 4; ++mi)
      af[mi] = *(const bf16x8*)&As[(wr * 64 + mi * 16 + lrow) * 32 + lk];
    #pragma unroll
    for (int ni = 0; ni < 4; ++ni)
      bfr[ni] = *(const bf16x8*)&Bs[(wc * 64 + ni * 16 + lrow) * 32 + lk];
    #pragma unroll
    for (int mi = 0; mi < 4; ++mi)
      #pragma unroll
      for (int ni = 0; ni < 4; ++ni)
        acc[mi][ni] = __builtin_amdgcn_mfma_f32_16x16x32_bf16(af[mi], bfr[ni], acc[mi][ni], 0, 0, 0);
    __syncthreads();
  }
  const int lcol = lane & 15, rgrp = lane >> 4;
  #pragma unroll
  for (int mi = 0; mi < 4; ++mi)
    #pragma unroll
    for (int ni = 0; ni < 4; ++ni) {
      const int col = col0 + wc * 64 + ni * 16 + lcol;
      if (col >= N) continue;
      const int rbase = row0 + wr * 64 + mi * 16 + rgrp * 4;
      #pragma unroll
      for (int r = 0; r < 4; ++r) {
        const int rr = rbase + r;
        if (rr >= M) continue;
        fout[(size_t)rr * N + col] = acc[mi][ni][r];
      }
    }
}

// ---------------- LayerNorm over bf16 t: one wave per token ----------------
__global__ __launch_bounds__(256) void ln_kernel(
    const bf16_t* __restrict__ t, const float* __restrict__ w,
    const float* __restrict__ b, bf16_t* __restrict__ y)
{
  const int token = blockIdx.x * 4 + (threadIdx.x >> 6);
  const int lane  = threadIdx.x & 63;
  const bf16_t* xp = t + (size_t)token * EDIM;
  // lane covers elems [lane*8, lane*8+8) and [512 + lane*4, 512 + lane*4+4)
  const bf16x8 a8 = *(const bf16x8*)(xp + lane * 8);
  const bf16x4 a4 = *(const bf16x4*)(xp + 512 + lane * 4);
  float va[12];
  #pragma unroll
  for (int j = 0; j < 8; ++j) va[j] = (float)a8[j];
  #pragma unroll
  for (int j = 0; j < 4; ++j) va[8 + j] = (float)a4[j];
  float s = 0.f;
  #pragma unroll
  for (int j = 0; j < 12; ++j) s += va[j];
  #pragma unroll
  for (int off = 32; off; off >>= 1) s += __shfl_xor(s, off);
  const float mu = s * (1.f / 768.f);
  float q = 0.f;
  #pragma unroll
  for (int j = 0; j < 12; ++j) { const float d = va[j] - mu; q += d * d; }
  #pragma unroll
  for (int off = 32; off; off >>= 1) q += __shfl_xor(q, off);
  const float rs = rsqrtf(q * (1.f / 768.f) + 1e-6f);

  bf16_t* yp = y + (size_t)token * EDIM;
  {
    const int e0 = lane * 8;
    const float4 w0 = ((const float4*)(w + e0))[0];
    const float4 w1 = ((const float4*)(w + e0))[1];
    const float4 b0 = ((const float4*)(b + e0))[0];
    const float4 b1 = ((const float4*)(b + e0))[1];
    bf16x8 o;
    o[0] = (bf16_t)((va[0] - mu) * rs * w0.x + b0.x);
    o[1] = (bf16_t)((va[1] - mu) * rs * w0.y + b0.y);
    o[2] = (bf16_t)((va[2] - mu) * rs * w0.z + b0.z);
    o[3] = (bf16_t)((va[3] - mu) * rs * w0.w + b0.w);
    o[4] = (bf16_t)((va[4] - mu) * rs * w1.x + b1.x);
    o[5] = (bf16_t)((va[5] - mu) * rs * w1.y + b1.y);
    o[6] = (bf16_t)((va[6] - mu) * rs * w1.z + b1.z);
    o[7] = (bf16_t)((va[7] - mu) * rs * w1.w + b1.w);
    *(bf16x8*)(yp + e0) = o;
  }
  {
    const int e0 = 512 + lane * 4;
    const float4 w0 = *(const float4*)(w + e0);
    const float4 b0 = *(const float4*)(b + e0);
    bf16x4 o;
    o[0] = (bf16_t)((va[8]  - mu) * rs * w0.x + b0.x);
    o[1] = (bf16_t)((va[9]  - mu) * rs * w0.y + b0.y);
    o[2] = (bf16_t)((va[10] - mu) * rs * w0.z + b0.z);
    o[3] = (bf16_t)((va[11] - mu) * rs * w0.w + b0.w);
    *(bf16x4*)(yp + e0) = o;
  }
}

// ---------------- row-wise attention: block per (b_local, s1, h) -----------
__global__ __launch_bounds__(256) void attn_kernel(
    const bf16_t* __restrict__ qkv, bf16_t* __restrict__ o)
{
  const int blk = blockIdx.x;
  const int h  = blk % 12;
  const int bs = blk / 12;
  const int s1 = bs % SDIM;
  const int b  = bs / SDIM;
  __shared__ float Qs[SDIM][65], Ks[SDIM][65], Vs[SDIM][65], Ps[SDIM][44];
  const int tid = threadIdx.x;
  const size_t base = ((size_t)b * LLEN + (size_t)s1 * SDIM);

  for (int idx = tid; idx < SDIM * 8; idx += 256) {
    const int m = idx >> 3, c = idx & 7;
    const bf16_t* p = qkv + (base + m) * 2304 + h * 64 + c * 8;
    const bf16x8 qv = *(const bf16x8*)(p);
    const bf16x8 kv = *(const bf16x8*)(p + 768);
    const bf16x8 vv = *(const bf16x8*)(p + 1536);
    #pragma unroll
    for (int j = 0; j < 8; ++j) {
      Qs[m][c * 8 + j] = (float)qv[j];
      Ks[m][c * 8 + j] = (float)kv[j];
      Vs[m][c * 8 + j] = (float)vv[j];
    }
  }
  __syncthreads();

  for (int idx = tid; idx < SDIM * SDIM; idx += 256) {
    const int n = idx / SDIM, m = idx % SDIM;
    float s = 0.f;
    #pragma unroll
    for (int d = 0; d < 64; ++d) s += Qs[n][d] * Ks[m][d];
    Ps[n][m] = s * 0.125f;
  }
  __syncthreads();

  {
    const int row = tid >> 2, sub = tid & 3;
    if (row < SDIM) {
      float mx = -1e30f;
      for (int m = sub; m < SDIM; m += 4) mx = fmaxf(mx, Ps[row][m]);
      mx = fmaxf(mx, __shfl_xor(mx, 1));
      mx = fmaxf(mx, __shfl_xor(mx, 2));
      float sum = 0.f;
      for (int m = sub; m < SDIM; m += 4) {
        const float e = __expf(Ps[row][m] - mx);
        Ps[row][m] = e;
        sum += e;
      }
      sum += __shfl_xor(sum, 1);
      sum += __shfl_xor(sum, 2);
      const float inv = 1.f / sum;
      for (int m = sub; m < SDIM; m += 4) Ps[row][m] *= inv;
    }
  }
  __syncthreads();

  for (int idx = tid; idx < SDIM * 64; idx += 256) {
    const int n = idx >> 6, d = idx & 63;
    float s = 0.f;
    #pragma unroll
    for (int m = 0; m < SDIM; ++m) s += Ps[n][m] * Vs[m][d];
    o[(base + n) * EDIM + h * 64 + d] = (bf16_t)s;
  }
}

// ---------------- transpose fp32(KxN) -> bf16(NxK) ----------------
__global__ __launch_bounds__(256) void transpose_kernel(
    const float* __restrict__ in, bf16_t* __restrict__ out, int K, int N)
{
  __shared__ float tile[32][33];
  const int k0 = blockIdx.x * 32, n0 = blockIdx.y * 32;
  const int tx = threadIdx.x & 31, ty = threadIdx.x >> 5;
  #pragma unroll
  for (int i = 0; i < 32; i += 8) {
    const int k = k0 + ty + i, n = n0 + tx;
    if (k < K && n < N) tile[ty + i][tx] = in[(size_t)k * N + n];
  }
  __syncthreads();
  #pragma unroll
  for (int i = 0; i < 32; i += 8) {
    const int n = n0 + ty + i, k = k0 + tx;
    if (n < N && k < K) out[(size_t)n * K + k] = (bf16_t)tile[tx][ty + i];
  }
}

// ---------------- im2col for conv1 chunk (pad K 1200->1216) ----------------
__global__ __launch_bounds__(256) void im2col_kernel(
    const float* __restrict__ x, bf16_t* __restrict__ col, int tok0, int ntok)
{
  const size_t idx = (size_t)blockIdx.x * 256 + threadIdx.x;
  if (idx >= (size_t)ntok * 1216) return;
  const int kk = (int)(idx % 1216);
  const size_t tok = tok0 + idx / 1216;
  const int b = (int)(tok / LLEN), l = (int)(tok % LLEN);
  const int s1 = l / SDIM, s2 = l % SDIM;
  float v = 0.f;
  if (kk < 1200) {
    const int cin = kk / 100, r = kk % 100, ky = r / 10, kx = r % 10;
    const int iy = s1 - 5 + ky, ix = s2 - 5 + kx;
    if (iy >= 0 && iy < 40 && ix >= 0 && ix < 40)
      v = x[((size_t)(b * 12 + cin) * 40 + iy) * 40 + ix];
  }
  col[idx] = (bf16_t)v;
}

__global__ __launch_bounds__(256) void convw_kernel(
    const float* __restrict__ w, bf16_t* __restrict__ out)
{
  const int idx = blockIdx.x * 256 + threadIdx.x;
  const int kk = idx % 1216, e = idx / 1216;
  const float v = (kk < 1200) ? w[(size_t)e * 1200 + kk] : 0.f;
  out[idx] = (bf16_t)v;
}

__global__ __launch_bounds__(256) void tconvw_kernel(
    const float* __restrict__ w, bf16_t* __restrict__ out)
{
  const int idx = blockIdx.x * 256 + threadIdx.x;  // 100*768
  const int e = idx % 768, tap = idx / 768;
  const int ky = tap / 10, kx = tap % 10;
  out[idx] = (bf16_t)w[(size_t)e * 100 + (9 - ky) * 10 + (9 - kx)];
}

// ---------------- final gather ----------------
__global__ __launch_bounds__(256) void outconv_kernel(
    const float* __restrict__ g, const float* __restrict__ tb,
    float* __restrict__ out)
{
  const int idx = blockIdx.x * 256 + threadIdx.x;
  if (idx >= 16 * 40 * 40) return;
  const int x = idx % 40, y = (idx / 40) % 40, b = idx / 1600;
  float s = tb[0];
  #pragma unroll
  for (int ky = 0; ky < 10; ++ky) {
    const int ty_ = y - 4 + ky;
    if (ty_ < 0 || ty_ >= SDIM) continue;
    #pragma unroll
    for (int kx = 0; kx < 10; ++kx) {
      const int tx_ = x - 4 + kx;
      if (tx_ < 0 || tx_ >= SDIM) continue;
      s += g[((size_t)b * LLEN + ty_ * SDIM + tx_) * 100 + ky * 10 + kx];
    }
  }
  out[idx] = s;
}

// ============================================================================
extern "C" void kernel_launch(void* const* d_in, const int* in_sizes, int n_in,
                              void* d_out, int out_size, void* d_ws, size_t ws_size,
                              hipStream_t stream)
{
  const float* x       = (const float*)d_in[0];
  const float* conv_w  = (const float*)d_in[1];
  const float* conv_b  = (const float*)d_in[2];
  const float* pos     = (const float*)d_in[3];
  const float* ln1_w   = (const float*)d_in[4];
  const float* ln1_b   = (const float*)d_in[5];
  const float* qkv_w   = (const float*)d_in[6];
  const float* qkv_b   = (const float*)d_in[7];
  const float* proj_w  = (const float*)d_in[8];
  const float* proj_b  = (const float*)d_in[9];
  const float* ln2_w   = (const float*)d_in[10];
  const float* ln2_b   = (const float*)d_in[11];
  const float* fc1_w   = (const float*)d_in[12];
  const float* fc1_b   = (const float*)d_in[13];
  const float* fc2_w   = (const float*)d_in[14];
  const float* fc2_b   = (const float*)d_in[15];
  const float* lnf_w   = (const float*)d_in[16];
  const float* lnf_b   = (const float*)d_in[17];
  const float* tconv_w = (const float*)d_in[18];
  const float* tconv_b = (const float*)d_in[19];
  float* out = (float*)d_out;

  // ---- workspace tiers (t now bf16): nch=1 262MB / nch=2 180MB / nch=4 138MB
  const int nch = (ws_size >= 262200000UL) ? 1
                : (ws_size >= 179500000UL) ? 2 : 4;
  const int cht = TOKENS / nch;

  char* p = (char*)d_ws;
  auto alloc = [&](size_t bytes) {
    char* r = p;
    p += (bytes + 255) & ~(size_t)255;
    return r;
  };
  bf16_t* wbuf = (bf16_t*)alloc((size_t)768 * 9216 * 2);
  bf16_t* t    = (bf16_t*)alloc((size_t)TOKENS * EDIM * 2);   // bf16 residual
  bf16_t* ybuf = (bf16_t*)alloc((size_t)TOKENS * EDIM * 2);
  bf16_t* hbuf = (bf16_t*)alloc((size_t)cht * 3072 * 2);

  bf16_t* Wq = wbuf;
  bf16_t* Wp = Wq + (size_t)2304 * 768;
  bf16_t* W1 = Wp + (size_t)768 * 768;
  bf16_t* W2 = W1 + (size_t)3072 * 768;

  auto g4 = [&](int epi, const bf16_t* A, const bf16_t* Bt,
                const float* bias, bf16_t* bo, const float* pe,
                int M, int N, int K) {
    const int mtiles = (M + 127) / 128;
    const int ntn = N / 128;
    const int nwg = mtiles * ntn;
    switch (epi) {
      case EPI_T_POS: gemm4_kernel<EPI_T_POS><<<nwg, 256, 0, stream>>>(A, Bt, bias, nullptr, bo, pe, M, N, K, ntn, nwg); break;
      case EPI_BF16:  gemm4_kernel<EPI_BF16 ><<<nwg, 256, 0, stream>>>(A, Bt, bias, nullptr, bo, pe, M, N, K, ntn, nwg); break;
      case EPI_ADD_T: gemm4_kernel<EPI_ADD_T><<<nwg, 256, 0, stream>>>(A, Bt, bias, nullptr, bo, pe, M, N, K, ntn, nwg); break;
      default:        gemm4_kernel<EPI_GELU ><<<nwg, 256, 0, stream>>>(A, Bt, bias, nullptr, bo, pe, M, N, K, ntn, nwg); break;
    }
  };

  // ---- conv1 as chunked im2col GEMM -> t (+bias +pos_embed), bf16 ----
  convw_kernel<<<(768 * 1216) / 256, 256, 0, stream>>>(conv_w, wbuf);
  for (int c = 0; c < nch; ++c) {
    const int tok0 = c * cht;
    im2col_kernel<<<(unsigned)(((size_t)cht * 1216 + 255) / 256), 256, 0, stream>>>(x, hbuf, tok0, cht);
    g4(EPI_T_POS, hbuf, wbuf, conv_b, t + (size_t)tok0 * EDIM, pos, cht, EDIM, 1216);
  }

  // ---- transformer layers ----
  for (int i = 0; i < 12; ++i) {
    transpose_kernel<<<dim3(24, 72), 256, 0, stream>>>(qkv_w + (size_t)i * 768 * 2304, Wq, 768, 2304);
    transpose_kernel<<<dim3(24, 24), 256, 0, stream>>>(proj_w + (size_t)i * 768 * 768, Wp, 768, 768);
    transpose_kernel<<<dim3(24, 96), 256, 0, stream>>>(fc1_w + (size_t)i * 768 * 3072, W1, 768, 3072);
    transpose_kernel<<<dim3(96, 24), 256, 0, stream>>>(fc2_w + (size_t)i * 3072 * 768, W2, 3072, 768);

    ln_kernel<<<TOKENS / 4, 256, 0, stream>>>(t, ln1_w + i * EDIM, ln1_b + i * EDIM, ybuf);
    for (int c = 0; c < nch; ++c) {
      const size_t ro = (size_t)c * cht;
      g4(EPI_BF16, ybuf + ro * EDIM, Wq, qkv_b + i * 2304, hbuf, nullptr, cht, 2304, 768);
      attn_kernel<<<(16 / nch) * SDIM * 12, 256, 0, stream>>>(hbuf, ybuf + ro * EDIM);
    }
    g4(EPI_ADD_T, ybuf, Wp, proj_b + i * EDIM, t, nullptr, TOKENS, EDIM, 768);

    ln_kernel<<<TOKENS / 4, 256, 0, stream>>>(t, ln2_w + i * EDIM, ln2_b + i * EDIM, ybuf);
    for (int c = 0; c < nch; ++c) {
      const size_t ro = (size_t)c * cht;
      g4(EPI_GELU, ybuf + ro * EDIM, W1, fc1_b + i * 3072, hbuf, nullptr, cht, 3072, 768);
      g4(EPI_ADD_T, hbuf, W2, fc2_b + i * EDIM, t + ro * EDIM, nullptr, cht, EDIM, 3072);
    }
  }

  // ---- final LN + tconv head ----
  ln_kernel<<<TOKENS / 4, 256, 0, stream>>>(t, lnf_w, lnf_b, ybuf);
  tconvw_kernel<<<(100 * 768) / 256, 256, 0, stream>>>(tconv_w, wbuf);
  gemm128_f32<<<dim3((TOKENS + 127) / 128, 1), 256, 0, stream>>>(ybuf, wbuf, (float*)hbuf, TOKENS, 100, 768);
  outconv_kernel<<<100, 256, 0, stream>>>((const float*)hbuf, tconv_b, out);
}

// Round 10
// 10004.633 us; speedup vs baseline: 1.3920x; 1.0198x over previous
//
#include <hip/hip_runtime.h>
#include <cstdint>

typedef __bf16 bf16_t;
typedef __attribute__((ext_vector_type(8))) __bf16 bf16x8;
typedef __attribute__((ext_vector_type(4))) __bf16 bf16x4;
typedef __attribute__((ext_vector_type(4))) float f32x4;

#define TOKENS 26896
#define LLEN   1681
#define SDIM   41
#define EDIM   768

// ---------------- async global->LDS 16B ----------------
__device__ __forceinline__ void gload_lds16(const bf16_t* g, bf16_t* l) {
  auto gp = reinterpret_cast<const __attribute__((address_space(1))) char*>(
      reinterpret_cast<uintptr_t>(g));
  auto lp = reinterpret_cast<__attribute__((address_space(3))) char*>(
      reinterpret_cast<uintptr_t>(l));
  __builtin_amdgcn_global_load_lds(gp, lp, 16, 0, 0);
}

enum { EPI_T_POS = 0, EPI_BF16 = 1, EPI_ADD_T = 2, EPI_GELU = 3, EPI_F32 = 4 };

// ============================================================================
// gemm4r: gemm4 + ring-3 counted-vmcnt (T4). C = A(MxK,bf16) @ Bt(NxK,bf16)^T
// 128x128 tile, BK=32, 256 thr (2x2 waves, 64x64/wave), ring-3 LDS 48KB
// -> 3 blocks/CU. Counted vmcnt(4) at step end (never 0 mid-loop): slot t+1's
// loads (issued at t-1) retire; slot t+2's stay in flight across the barrier.
// Raw s_barrier + sched_barrier(0) (no compiler vmcnt(0) drain). Compile-time
// slot parity via unroll-by-3 (R6 lesson). XOR-swizzled LDS (0 conflicts
// measured R3-R9). Row-major tile order + bijective XCD swizzle.
// ============================================================================
template <int EPI>
__global__ __launch_bounds__(256, 3) void gemm4_kernel(
    const bf16_t* __restrict__ A, const bf16_t* __restrict__ Bt,
    const float* __restrict__ bias, float* __restrict__ fout,
    bf16_t* __restrict__ bout, const float* __restrict__ pos,
    int M, int N, int K, int ntn, int nwg)
{
  __shared__ bf16_t lds[3 * 8192];   // 3 ring slots x (A:128x32 + B:128x32)
  const int tid = threadIdx.x, wave = tid >> 6, lane = tid & 63;
  const int wr = wave >> 1, wc = wave & 1;

  int id = blockIdx.x;
  {
    const int q = nwg >> 3, r = nwg & 7;
    const int xcd = id & 7, ix = id >> 3;
    id = (xcd < r ? xcd * (q + 1) : r * (q + 1) + (xcd - r) * q) + ix;
  }
  const int row0 = (id / ntn) * 128;
  const int col0 = (id % ntn) * 128;
  const int NT = K >> 5;

  const int srow = tid >> 2;                                  // 0..63
  const int sswz = ((tid & 3) ^ ((srow >> 1) & 3)) * 8;       // inv-swz src col
  const bf16_t* aptr[2];
  const bf16_t* bptr[2];
  #pragma unroll
  for (int p = 0; p < 2; ++p) {
    int ar = row0 + p * 64 + srow; if (ar > M - 1) ar = M - 1;
    int br = col0 + p * 64 + srow; if (br > N - 1) br = N - 1;
    aptr[p] = A  + (size_t)ar * K + sswz;
    bptr[p] = Bt + (size_t)br * K + sswz;
  }
  bf16_t* sdst = lds + tid * 8;

  #define STAGE(BUF, KT) do {                                   \
    const int koff_ = (KT) << 5;                                \
    gload_lds16(aptr[0] + koff_, sdst + (BUF)*8192);            \
    gload_lds16(aptr[1] + koff_, sdst + (BUF)*8192 + 2048);     \
    gload_lds16(bptr[0] + koff_, sdst + (BUF)*8192 + 4096);     \
    gload_lds16(bptr[1] + koff_, sdst + (BUF)*8192 + 6144);     \
  } while (0)

  const int l15 = lane & 15, l4 = lane >> 4;
  const int fswz = (l4 ^ ((l15 >> 1) & 3)) << 3;
  const bf16_t* lA = lds + (wr * 64 + l15) * 32 + fswz;
  const bf16_t* lB = lds + 4096 + (wc * 64 + l15) * 32 + fswz;

  f32x4 acc[4][4] = {};

  #define COMPUTE(BUF) do {                                     \
    bf16x8 fa[4], fb[4];                                        \
    _Pragma("unroll")                                           \
    for (int m_ = 0; m_ < 4; ++m_) fa[m_] = *(const bf16x8*)(lA + (BUF)*8192 + m_*512); \
    _Pragma("unroll")                                           \
    for (int n_ = 0; n_ < 4; ++n_) fb[n_] = *(const bf16x8*)(lB + (BUF)*8192 + n_*512); \
    _Pragma("unroll")                                           \
    for (int m_ = 0; m_ < 4; ++m_)                              \
      _Pragma("unroll")                                         \
      for (int n_ = 0; n_ < 4; ++n_)                            \
        acc[m_][n_] = __builtin_amdgcn_mfma_f32_16x16x32_bf16(fa[m_], fb[n_], acc[m_][n_], 0, 0, 0); \
  } while (0)

  // one pipeline step: stage slot SN with tile T+2, compute slot SC (tile T),
  // counted wait, publish.
  #define STEP(SC, SN, T) do {                                  \
    if ((T) + 2 < NT) STAGE(SN, (T) + 2);                       \
    COMPUTE(SC);                                                \
    if ((T) + 2 < NT)      asm volatile("s_waitcnt vmcnt(4)" ::: "memory"); \
    else if ((T) + 1 < NT) asm volatile("s_waitcnt vmcnt(0)" ::: "memory"); \
    __builtin_amdgcn_s_barrier();                               \
    __builtin_amdgcn_sched_barrier(0);                          \
  } while (0)

  // prologue: stage tiles 0,1; retire tile 0; publish
  STAGE(0, 0);
  if (NT > 1) {
    STAGE(1, 1);
    asm volatile("s_waitcnt vmcnt(4)" ::: "memory");
  } else {
    asm volatile("s_waitcnt vmcnt(0)" ::: "memory");
  }
  __builtin_amdgcn_s_barrier();
  __builtin_amdgcn_sched_barrier(0);

  for (int kt = 0; kt < NT; kt += 3) {
    STEP(0, 2, kt);
    if (kt + 1 < NT) STEP(1, 0, kt + 1);
    if (kt + 2 < NT) STEP(2, 1, kt + 2);
  }
  #undef STEP
  #undef STAGE
  #undef COMPUTE

  const int rgrp = lane >> 4;
  #pragma unroll
  for (int m = 0; m < 4; ++m) {
    #pragma unroll
    for (int n = 0; n < 4; ++n) {
      const int col = col0 + wc * 64 + n * 16 + l15;
      if (col >= N) continue;
      const int rbase = row0 + wr * 64 + m * 16 + rgrp * 4;
      float bv = 0.f;
      if constexpr (EPI != EPI_F32) bv = bias[col];
      #pragma unroll
      for (int r = 0; r < 4; ++r) {
        const int rr = rbase + r;
        if (rr >= M) continue;
        const float v = acc[m][n][r] + bv;
        const size_t o = (size_t)rr * N + col;
        if constexpr (EPI == EPI_T_POS) {
          const int l = rr % LLEN;
          bout[o] = (bf16_t)(v + pos[(size_t)l * N + col]);
        } else if constexpr (EPI == EPI_BF16) {
          bout[o] = (bf16_t)v;
        } else if constexpr (EPI == EPI_ADD_T) {
          bout[o] = (bf16_t)((float)bout[o] + v);
        } else if constexpr (EPI == EPI_GELU) {
          // tanh-approx GELU in sigmoid form (~7 VALU + 1 exp vs erff ~25)
          const float u = v + 0.044715f * v * v * v;
          const float gg = v / (1.f + __expf(-1.5957691216f * u));
          bout[o] = (bf16_t)gg;
        } else {
          fout[o] = v;
        }
      }
    }
  }
}

// ---------------- head GEMM (N=100), simple 128x128 ----------------
__global__ __launch_bounds__(256) void gemm128_f32(
    const bf16_t* __restrict__ A, const bf16_t* __restrict__ Bt,
    float* __restrict__ fout, int M, int N, int K)
{
  __shared__ bf16_t As[128 * 32];
  __shared__ bf16_t Bs[128 * 32];
  const int tid = threadIdx.x, wave = tid >> 6, lane = tid & 63;
  const int row0 = blockIdx.x * 128, col0 = blockIdx.y * 128;
  const int wr = wave >> 1, wc = wave & 1;
  f32x4 acc[4][4] = {};
  const int srow = lane >> 2, skoff = (lane & 3) * 8;
  const int nsteps = K >> 5;
  for (int kt = 0; kt < nsteps; ++kt) {
    const int k0 = kt << 5;
    #pragma unroll
    for (int i = 0; i < 2; ++i) {
      const int r = (i * 4 + wave) * 16 + srow;
      int arow = row0 + r; if (arow > M - 1) arow = M - 1;
      int brow = col0 + r; if (brow > N - 1) brow = N - 1;
      gload_lds16(A  + (size_t)arow * K + k0 + skoff, &As[r * 32 + skoff]);
      gload_lds16(Bt + (size_t)brow * K + k0 + skoff, &Bs[r * 32 + skoff]);
    }
    asm volatile("s_waitcnt vmcnt(0)" ::: "memory");
    __syncthreads();
    const int lrow = lane & 15, lk = (lane >> 4) * 8;
    bf16x8 af[4], bfr[4];
    #pragma unroll
    for (int mi = 0; mi < 4; ++mi)
      af[mi] = *(const bf16x8*)&As[(wr * 64 + mi * 16 + lrow) * 32 + lk];
    #pragma unroll
    for (int ni = 0; ni < 4; ++ni)
      bfr[ni] = *(const bf16x8*)&Bs[(wc * 64 + ni * 16 + lrow) * 32 + lk];
    #pragma unroll
    for (int mi = 0; mi < 4; ++mi)
      #pragma unroll
      for (int ni = 0; ni < 4; ++ni)
        acc[mi][ni] = __builtin_amdgcn_mfma_f32_16x16x32_bf16(af[mi], bfr[ni], acc[mi][ni], 0, 0, 0);
    __syncthreads();
  }
  const int lcol = lane & 15, rgrp = lane >> 4;
  #pragma unroll
  for (int mi = 0; mi < 4; ++mi)
    #pragma unroll
    for (int ni = 0; ni < 4; ++ni) {
      const int col = col0 + wc * 64 + ni * 16 + lcol;
      if (col >= N) continue;
      const int rbase = row0 + wr * 64 + mi * 16 + rgrp * 4;
      #pragma unroll
      for (int r = 0; r < 4; ++r) {
        const int rr = rbase + r;
        if (rr >= M) continue;
        fout[(size_t)rr * N + col] = acc[mi][ni][r];
      }
    }
}

// ---------------- LayerNorm over bf16 t: one wave per token ----------------
__global__ __launch_bounds__(256) void ln_kernel(
    const bf16_t* __restrict__ t, const float* __restrict__ w,
    const float* __restrict__ b, bf16_t* __restrict__ y)
{
  const int token = blockIdx.x * 4 + (threadIdx.x >> 6);
  const int lane  = threadIdx.x & 63;
  const bf16_t* xp = t + (size_t)token * EDIM;
  const bf16x8 a8 = *(const bf16x8*)(xp + lane * 8);
  const bf16x4 a4 = *(const bf16x4*)(xp + 512 + lane * 4);
  float va[12];
  #pragma unroll
  for (int j = 0; j < 8; ++j) va[j] = (float)a8[j];
  #pragma unroll
  for (int j = 0; j < 4; ++j) va[8 + j] = (float)a4[j];
  float s = 0.f;
  #pragma unroll
  for (int j = 0; j < 12; ++j) s += va[j];
  #pragma unroll
  for (int off = 32; off; off >>= 1) s += __shfl_xor(s, off);
  const float mu = s * (1.f / 768.f);
  float q = 0.f;
  #pragma unroll
  for (int j = 0; j < 12; ++j) { const float d = va[j] - mu; q += d * d; }
  #pragma unroll
  for (int off = 32; off; off >>= 1) q += __shfl_xor(q, off);
  const float rs = rsqrtf(q * (1.f / 768.f) + 1e-6f);

  bf16_t* yp = y + (size_t)token * EDIM;
  {
    const int e0 = lane * 8;
    const float4 w0 = ((const float4*)(w + e0))[0];
    const float4 w1 = ((const float4*)(w + e0))[1];
    const float4 b0 = ((const float4*)(b + e0))[0];
    const float4 b1 = ((const float4*)(b + e0))[1];
    bf16x8 o;
    o[0] = (bf16_t)((va[0] - mu) * rs * w0.x + b0.x);
    o[1] = (bf16_t)((va[1] - mu) * rs * w0.y + b0.y);
    o[2] = (bf16_t)((va[2] - mu) * rs * w0.z + b0.z);
    o[3] = (bf16_t)((va[3] - mu) * rs * w0.w + b0.w);
    o[4] = (bf16_t)((va[4] - mu) * rs * w1.x + b1.x);
    o[5] = (bf16_t)((va[5] - mu) * rs * w1.y + b1.y);
    o[6] = (bf16_t)((va[6] - mu) * rs * w1.z + b1.z);
    o[7] = (bf16_t)((va[7] - mu) * rs * w1.w + b1.w);
    *(bf16x8*)(yp + e0) = o;
  }
  {
    const int e0 = 512 + lane * 4;
    const float4 w0 = *(const float4*)(w + e0);
    const float4 b0 = *(const float4*)(b + e0);
    bf16x4 o;
    o[0] = (bf16_t)((va[8]  - mu) * rs * w0.x + b0.x);
    o[1] = (bf16_t)((va[9]  - mu) * rs * w0.y + b0.y);
    o[2] = (bf16_t)((va[10] - mu) * rs * w0.z + b0.z);
    o[3] = (bf16_t)((va[11] - mu) * rs * w0.w + b0.w);
    *(bf16x4*)(yp + e0) = o;
  }
}

// ---------------- row-wise attention: block per (b_local, s1, h) -----------
__global__ __launch_bounds__(256) void attn_kernel(
    const bf16_t* __restrict__ qkv, bf16_t* __restrict__ o)
{
  const int blk = blockIdx.x;
  const int h  = blk % 12;
  const int bs = blk / 12;
  const int s1 = bs % SDIM;
  const int b  = bs / SDIM;
  __shared__ float Qs[SDIM][65], Ks[SDIM][65], Vs[SDIM][65], Ps[SDIM][44];
  const int tid = threadIdx.x;
  const size_t base = ((size_t)b * LLEN + (size_t)s1 * SDIM);

  for (int idx = tid; idx < SDIM * 8; idx += 256) {
    const int m = idx >> 3, c = idx & 7;
    const bf16_t* p = qkv + (base + m) * 2304 + h * 64 + c * 8;
    const bf16x8 qv = *(const bf16x8*)(p);
    const bf16x8 kv = *(const bf16x8*)(p + 768);
    const bf16x8 vv = *(const bf16x8*)(p + 1536);
    #pragma unroll
    for (int j = 0; j < 8; ++j) {
      Qs[m][c * 8 + j] = (float)qv[j];
      Ks[m][c * 8 + j] = (float)kv[j];
      Vs[m][c * 8 + j] = (float)vv[j];
    }
  }
  __syncthreads();

  for (int idx = tid; idx < SDIM * SDIM; idx += 256) {
    const int n = idx / SDIM, m = idx % SDIM;
    float s = 0.f;
    #pragma unroll
    for (int d = 0; d < 64; ++d) s += Qs[n][d] * Ks[m][d];
    Ps[n][m] = s * 0.125f;
  }
  __syncthreads();

  {
    const int row = tid >> 2, sub = tid & 3;
    if (row < SDIM) {
      float mx = -1e30f;
      for (int m = sub; m < SDIM; m += 4) mx = fmaxf(mx, Ps[row][m]);
      mx = fmaxf(mx, __shfl_xor(mx, 1));
      mx = fmaxf(mx, __shfl_xor(mx, 2));
      float sum = 0.f;
      for (int m = sub; m < SDIM; m += 4) {
        const float e = __expf(Ps[row][m] - mx);
        Ps[row][m] = e;
        sum += e;
      }
      sum += __shfl_xor(sum, 1);
      sum += __shfl_xor(sum, 2);
      const float inv = 1.f / sum;
      for (int m = sub; m < SDIM; m += 4) Ps[row][m] *= inv;
    }
  }
  __syncthreads();

  for (int idx = tid; idx < SDIM * 64; idx += 256) {
    const int n = idx >> 6, d = idx & 63;
    float s = 0.f;
    #pragma unroll
    for (int m = 0; m < SDIM; ++m) s += Ps[n][m] * Vs[m][d];
    o[(base + n) * EDIM + h * 64 + d] = (bf16_t)s;
  }
}

// ---------------- transpose fp32(KxN) -> bf16(NxK) ----------------
__global__ __launch_bounds__(256) void transpose_kernel(
    const float* __restrict__ in, bf16_t* __restrict__ out, int K, int N)
{
  __shared__ float tile[32][33];
  const int k0 = blockIdx.x * 32, n0 = blockIdx.y * 32;
  const int tx = threadIdx.x & 31, ty = threadIdx.x >> 5;
  #pragma unroll
  for (int i = 0; i < 32; i += 8) {
    const int k = k0 + ty + i, n = n0 + tx;
    if (k < K && n < N) tile[ty + i][tx] = in[(size_t)k * N + n];
  }
  __syncthreads();
  #pragma unroll
  for (int i = 0; i < 32; i += 8) {
    const int n = n0 + ty + i, k = k0 + tx;
    if (n < N && k < K) out[(size_t)n * K + k] = (bf16_t)tile[tx][ty + i];
  }
}

// ---------------- im2col for conv1 chunk (pad K 1200->1216) ----------------
__global__ __launch_bounds__(256) void im2col_kernel(
    const float* __restrict__ x, bf16_t* __restrict__ col, int tok0, int ntok)
{
  const size_t idx = (size_t)blockIdx.x * 256 + threadIdx.x;
  if (idx >= (size_t)ntok * 1216) return;
  const int kk = (int)(idx % 1216);
  const size_t tok = tok0 + idx / 1216;
  const int b = (int)(tok / LLEN), l = (int)(tok % LLEN);
  const int s1 = l / SDIM, s2 = l % SDIM;
  float v = 0.f;
  if (kk < 1200) {
    const int cin = kk / 100, r = kk % 100, ky = r / 10, kx = r % 10;
    const int iy = s1 - 5 + ky, ix = s2 - 5 + kx;
    if (iy >= 0 && iy < 40 && ix >= 0 && ix < 40)
      v = x[((size_t)(b * 12 + cin) * 40 + iy) * 40 + ix];
  }
  col[idx] = (bf16_t)v;
}

__global__ __launch_bounds__(256) void convw_kernel(
    const float* __restrict__ w, bf16_t* __restrict__ out)
{
  const int idx = blockIdx.x * 256 + threadIdx.x;
  const int kk = idx % 1216, e = idx / 1216;
  const float v = (kk < 1200) ? w[(size_t)e * 1200 + kk] : 0.f;
  out[idx] = (bf16_t)v;
}

__global__ __launch_bounds__(256) void tconvw_kernel(
    const float* __restrict__ w, bf16_t* __restrict__ out)
{
  const int idx = blockIdx.x * 256 + threadIdx.x;  // 100*768
  const int e = idx % 768, tap = idx / 768;
  const int ky = tap / 10, kx = tap % 10;
  out[idx] = (bf16_t)w[(size_t)e * 100 + (9 - ky) * 10 + (9 - kx)];
}

// ---------------- final gather ----------------
__global__ __launch_bounds__(256) void outconv_kernel(
    const float* __restrict__ g, const float* __restrict__ tb,
    float* __restrict__ out)
{
  const int idx = blockIdx.x * 256 + threadIdx.x;
  if (idx >= 16 * 40 * 40) return;
  const int x = idx % 40, y = (idx / 40) % 40, b = idx / 1600;
  float s = tb[0];
  #pragma unroll
  for (int ky = 0; ky < 10; ++ky) {
    const int ty_ = y - 4 + ky;
    if (ty_ < 0 || ty_ >= SDIM) continue;
    #pragma unroll
    for (int kx = 0; kx < 10; ++kx) {
      const int tx_ = x - 4 + kx;
      if (tx_ < 0 || tx_ >= SDIM) continue;
      s += g[((size_t)b * LLEN + ty_ * SDIM + tx_) * 100 + ky * 10 + kx];
    }
  }
  out[idx] = s;
}

// ============================================================================
extern "C" void kernel_launch(void* const* d_in, const int* in_sizes, int n_in,
                              void* d_out, int out_size, void* d_ws, size_t ws_size,
                              hipStream_t stream)
{
  const float* x       = (const float*)d_in[0];
  const float* conv_w  = (const float*)d_in[1];
  const float* conv_b  = (const float*)d_in[2];
  const float* pos     = (const float*)d_in[3];
  const float* ln1_w   = (const float*)d_in[4];
  const float* ln1_b   = (const float*)d_in[5];
  const float* qkv_w   = (const float*)d_in[6];
  const float* qkv_b   = (const float*)d_in[7];
  const float* proj_w  = (const float*)d_in[8];
  const float* proj_b  = (const float*)d_in[9];
  const float* ln2_w   = (const float*)d_in[10];
  const float* ln2_b   = (const float*)d_in[11];
  const float* fc1_w   = (const float*)d_in[12];
  const float* fc1_b   = (const float*)d_in[13];
  const float* fc2_w   = (const float*)d_in[14];
  const float* fc2_b   = (const float*)d_in[15];
  const float* lnf_w   = (const float*)d_in[16];
  const float* lnf_b   = (const float*)d_in[17];
  const float* tconv_w = (const float*)d_in[18];
  const float* tconv_b = (const float*)d_in[19];
  float* out = (float*)d_out;

  // ---- workspace tiers (bf16 t): nch=1 262MB / nch=2 180MB / nch=4 138MB
  const int nch = (ws_size >= 262200000UL) ? 1
                : (ws_size >= 179500000UL) ? 2 : 4;
  const int cht = TOKENS / nch;

  char* p = (char*)d_ws;
  auto alloc = [&](size_t bytes) {
    char* r = p;
    p += (bytes + 255) & ~(size_t)255;
    return r;
  };
  bf16_t* wbuf = (bf16_t*)alloc((size_t)768 * 9216 * 2);
  bf16_t* t    = (bf16_t*)alloc((size_t)TOKENS * EDIM * 2);
  bf16_t* ybuf = (bf16_t*)alloc((size_t)TOKENS * EDIM * 2);
  bf16_t* hbuf = (bf16_t*)alloc((size_t)cht * 3072 * 2);

  bf16_t* Wq = wbuf;
  bf16_t* Wp = Wq + (size_t)2304 * 768;
  bf16_t* W1 = Wp + (size_t)768 * 768;
  bf16_t* W2 = W1 + (size_t)3072 * 768;

  auto g4 = [&](int epi, const bf16_t* A, const bf16_t* Bt,
                const float* bias, bf16_t* bo, const float* pe,
                int M, int N, int K) {
    const int mtiles = (M + 127) / 128;
    const int ntn = N / 128;
    const int nwg = mtiles * ntn;
    switch (epi) {
      case EPI_T_POS: gemm4_kernel<EPI_T_POS><<<nwg, 256, 0, stream>>>(A, Bt, bias, nullptr, bo, pe, M, N, K, ntn, nwg); break;
      case EPI_BF16:  gemm4_kernel<EPI_BF16 ><<<nwg, 256, 0, stream>>>(A, Bt, bias, nullptr, bo, pe, M, N, K, ntn, nwg); break;
      case EPI_ADD_T: gemm4_kernel<EPI_ADD_T><<<nwg, 256, 0, stream>>>(A, Bt, bias, nullptr, bo, pe, M, N, K, ntn, nwg); break;
      default:        gemm4_kernel<EPI_GELU ><<<nwg, 256, 0, stream>>>(A, Bt, bias, nullptr, bo, pe, M, N, K, ntn, nwg); break;
    }
  };

  // ---- conv1 as chunked im2col GEMM -> t (+bias +pos_embed), bf16 ----
  convw_kernel<<<(768 * 1216) / 256, 256, 0, stream>>>(conv_w, wbuf);
  for (int c = 0; c < nch; ++c) {
    const int tok0 = c * cht;
    im2col_kernel<<<(unsigned)(((size_t)cht * 1216 + 255) / 256), 256, 0, stream>>>(x, hbuf, tok0, cht);
    g4(EPI_T_POS, hbuf, wbuf, conv_b, t + (size_t)tok0 * EDIM, pos, cht, EDIM, 1216);
  }

  // ---- transformer layers ----
  for (int i = 0; i < 12; ++i) {
    transpose_kernel<<<dim3(24, 72), 256, 0, stream>>>(qkv_w + (size_t)i * 768 * 2304, Wq, 768, 2304);
    transpose_kernel<<<dim3(24, 24), 256, 0, stream>>>(proj_w + (size_t)i * 768 * 768, Wp, 768, 768);
    transpose_kernel<<<dim3(24, 96), 256, 0, stream>>>(fc1_w + (size_t)i * 768 * 3072, W1, 768, 3072);
    transpose_kernel<<<dim3(96, 24), 256, 0, stream>>>(fc2_w + (size_t)i * 3072 * 768, W2, 3072, 768);

    ln_kernel<<<TOKENS / 4, 256, 0, stream>>>(t, ln1_w + i * EDIM, ln1_b + i * EDIM, ybuf);
    for (int c = 0; c < nch; ++c) {
      const size_t ro = (size_t)c * cht;
      g4(EPI_BF16, ybuf + ro * EDIM, Wq, qkv_b + i * 2304, hbuf, nullptr, cht, 2304, 768);
      attn_kernel<<<(16 / nch) * SDIM * 12, 256, 0, stream>>>(hbuf, ybuf + ro * EDIM);
    }
    g4(EPI_ADD_T, ybuf, Wp, proj_b + i * EDIM, t, nullptr, TOKENS, EDIM, 768);

    ln_kernel<<<TOKENS / 4, 256, 0, stream>>>(t, ln2_w + i * EDIM, ln2_b + i * EDIM, ybuf);
    for (int c = 0; c < nch; ++c) {
      const size_t ro = (size_t)c * cht;
      g4(EPI_GELU, ybuf + ro * EDIM, W1, fc1_b + i * 3072, hbuf, nullptr, cht, 3072, 768);
      g4(EPI_ADD_T, hbuf, W2, fc2_b + i * EDIM, t + ro * EDIM, nullptr, cht, EDIM, 3072);
    }
  }

  // ---- final LN + tconv head ----
  ln_kernel<<<TOKENS / 4, 256, 0, stream>>>(t, lnf_w, lnf_b, ybuf);
  tconvw_kernel<<<(100 * 768) / 256, 256, 0, stream>>>(tconv_w, wbuf);
  gemm128_f32<<<dim3((TOKENS + 127) / 128, 1), 256, 0, stream>>>(ybuf, wbuf, (float*)hbuf, TOKENS, 100, 768);
  outconv_kernel<<<100, 256, 0, stream>>>((const float*)hbuf, tconv_b, out);
}

// Round 11
// 9774.034 us; speedup vs baseline: 1.4248x; 1.0236x over previous
//
#include <hip/hip_runtime.h>
#include <cstdint>

typedef __bf16 bf16_t;
typedef __attribute__((ext_vector_type(8))) __bf16 bf16x8;
typedef __attribute__((ext_vector_type(4))) __bf16 bf16x4;
typedef __attribute__((ext_vector_type(4))) float f32x4;

#define TOKENS 26896
#define LLEN   1681
#define SDIM   41
#define EDIM   768

// ---------------- async global->LDS 16B ----------------
__device__ __forceinline__ void gload_lds16(const bf16_t* g, bf16_t* l) {
  auto gp = reinterpret_cast<const __attribute__((address_space(1))) char*>(
      reinterpret_cast<uintptr_t>(g));
  auto lp = reinterpret_cast<__attribute__((address_space(3))) char*>(
      reinterpret_cast<uintptr_t>(l));
  __builtin_amdgcn_global_load_lds(gp, lp, 16, 0, 0);
}

enum { EPI_T_POS = 0, EPI_BF16 = 1, EPI_ADD_T = 2, EPI_GELU = 3, EPI_F32 = 4 };

// ============================================================================
// gemm4r (R10) + R11: L2-aware column-grouped tile order.
// 128x128 tile, BK=32, 256 thr, ring-3 LDS 48KB -> 3 blocks/CU, counted
// vmcnt(4), raw s_barrier + sched_barrier(0), XOR-swizzled LDS (0 conflicts).
// Tile order: XCD-bijective chunks; within a chunk, column-groups of 6
// panels swept row-major -> concurrent working set ~16 A-panels (3.1MB) +
// 6 B-panels (1.2MB) ~= 4MB L2 per XCD. (ntn divisible by 6 for all shapes.)
// ============================================================================
template <int EPI>
__global__ __launch_bounds__(256, 3) void gemm4_kernel(
    const bf16_t* __restrict__ A, const bf16_t* __restrict__ Bt,
    const float* __restrict__ bias, float* __restrict__ fout,
    bf16_t* __restrict__ bout, const float* __restrict__ pos,
    int M, int N, int K, int ntn, int nwg, int mtiles)
{
  __shared__ bf16_t lds[3 * 8192];   // 3 ring slots x (A:128x32 + B:128x32)
  const int tid = threadIdx.x, wave = tid >> 6, lane = tid & 63;
  const int wr = wave >> 1, wc = wave & 1;

  int id = blockIdx.x;
  {
    const int q = nwg >> 3, r = nwg & 7;
    const int xcd = id & 7, ix = id >> 3;
    id = (xcd < r ? xcd * (q + 1) : r * (q + 1) + (xcd - r) * q) + ix;
  }
  // column-grouped (NC=6) order: bijective since 6 | ntn for all shapes used
  const int gsz = mtiles * 6;
  const int cg  = id / gsz, rem = id % gsz;
  const int row0 = (rem / 6) * 128;
  const int col0 = (cg * 6 + rem % 6) * 128;
  const int NT = K >> 5;

  const int srow = tid >> 2;                                  // 0..63
  const int sswz = ((tid & 3) ^ ((srow >> 1) & 3)) * 8;       // inv-swz src col
  const bf16_t* aptr[2];
  const bf16_t* bptr[2];
  #pragma unroll
  for (int p = 0; p < 2; ++p) {
    int ar = row0 + p * 64 + srow; if (ar > M - 1) ar = M - 1;
    int br = col0 + p * 64 + srow; if (br > N - 1) br = N - 1;
    aptr[p] = A  + (size_t)ar * K + sswz;
    bptr[p] = Bt + (size_t)br * K + sswz;
  }
  bf16_t* sdst = lds + tid * 8;

  #define STAGE(BUF, KT) do {                                   \
    const int koff_ = (KT) << 5;                                \
    gload_lds16(aptr[0] + koff_, sdst + (BUF)*8192);            \
    gload_lds16(aptr[1] + koff_, sdst + (BUF)*8192 + 2048);     \
    gload_lds16(bptr[0] + koff_, sdst + (BUF)*8192 + 4096);     \
    gload_lds16(bptr[1] + koff_, sdst + (BUF)*8192 + 6144);     \
  } while (0)

  const int l15 = lane & 15, l4 = lane >> 4;
  const int fswz = (l4 ^ ((l15 >> 1) & 3)) << 3;
  const bf16_t* lA = lds + (wr * 64 + l15) * 32 + fswz;
  const bf16_t* lB = lds + 4096 + (wc * 64 + l15) * 32 + fswz;

  f32x4 acc[4][4] = {};

  #define COMPUTE(BUF) do {                                     \
    bf16x8 fa[4], fb[4];                                        \
    _Pragma("unroll")                                           \
    for (int m_ = 0; m_ < 4; ++m_) fa[m_] = *(const bf16x8*)(lA + (BUF)*8192 + m_*512); \
    _Pragma("unroll")                                           \
    for (int n_ = 0; n_ < 4; ++n_) fb[n_] = *(const bf16x8*)(lB + (BUF)*8192 + n_*512); \
    _Pragma("unroll")                                           \
    for (int m_ = 0; m_ < 4; ++m_)                              \
      _Pragma("unroll")                                         \
      for (int n_ = 0; n_ < 4; ++n_)                            \
        acc[m_][n_] = __builtin_amdgcn_mfma_f32_16x16x32_bf16(fa[m_], fb[n_], acc[m_][n_], 0, 0, 0); \
  } while (0)

  #define STEP(SC, SN, T) do {                                  \
    if ((T) + 2 < NT) STAGE(SN, (T) + 2);                       \
    COMPUTE(SC);                                                \
    if ((T) + 2 < NT)      asm volatile("s_waitcnt vmcnt(4)" ::: "memory"); \
    else if ((T) + 1 < NT) asm volatile("s_waitcnt vmcnt(0)" ::: "memory"); \
    __builtin_amdgcn_s_barrier();                               \
    __builtin_amdgcn_sched_barrier(0);                          \
  } while (0)

  STAGE(0, 0);
  if (NT > 1) {
    STAGE(1, 1);
    asm volatile("s_waitcnt vmcnt(4)" ::: "memory");
  } else {
    asm volatile("s_waitcnt vmcnt(0)" ::: "memory");
  }
  __builtin_amdgcn_s_barrier();
  __builtin_amdgcn_sched_barrier(0);

  for (int kt = 0; kt < NT; kt += 3) {
    STEP(0, 2, kt);
    if (kt + 1 < NT) STEP(1, 0, kt + 1);
    if (kt + 2 < NT) STEP(2, 1, kt + 2);
  }
  #undef STEP
  #undef STAGE
  #undef COMPUTE

  const int rgrp = lane >> 4;
  #pragma unroll
  for (int m = 0; m < 4; ++m) {
    #pragma unroll
    for (int n = 0; n < 4; ++n) {
      const int col = col0 + wc * 64 + n * 16 + l15;
      if (col >= N) continue;
      const int rbase = row0 + wr * 64 + m * 16 + rgrp * 4;
      float bv = 0.f;
      if constexpr (EPI != EPI_F32) bv = bias[col];
      #pragma unroll
      for (int r = 0; r < 4; ++r) {
        const int rr = rbase + r;
        if (rr >= M) continue;
        const float v = acc[m][n][r] + bv;
        const size_t o = (size_t)rr * N + col;
        if constexpr (EPI == EPI_T_POS) {
          const int l = rr % LLEN;
          bout[o] = (bf16_t)(v + pos[(size_t)l * N + col]);
        } else if constexpr (EPI == EPI_BF16) {
          bout[o] = (bf16_t)v;
        } else if constexpr (EPI == EPI_ADD_T) {
          bout[o] = (bf16_t)((float)bout[o] + v);
        } else if constexpr (EPI == EPI_GELU) {
          const float u = v + 0.044715f * v * v * v;
          const float gg = v / (1.f + __expf(-1.5957691216f * u));
          bout[o] = (bf16_t)gg;
        } else {
          fout[o] = v;
        }
      }
    }
  }
}

// ---------------- head GEMM (N=100), simple 128x128 ----------------
__global__ __launch_bounds__(256) void gemm128_f32(
    const bf16_t* __restrict__ A, const bf16_t* __restrict__ Bt,
    float* __restrict__ fout, int M, int N, int K)
{
  __shared__ bf16_t As[128 * 32];
  __shared__ bf16_t Bs[128 * 32];
  const int tid = threadIdx.x, wave = tid >> 6, lane = tid & 63;
  const int row0 = blockIdx.x * 128, col0 = blockIdx.y * 128;
  const int wr = wave >> 1, wc = wave & 1;
  f32x4 acc[4][4] = {};
  const int srow = lane >> 2, skoff = (lane & 3) * 8;
  const int nsteps = K >> 5;
  for (int kt = 0; kt < nsteps; ++kt) {
    const int k0 = kt << 5;
    #pragma unroll
    for (int i = 0; i < 2; ++i) {
      const int r = (i * 4 + wave) * 16 + srow;
      int arow = row0 + r; if (arow > M - 1) arow = M - 1;
      int brow = col0 + r; if (brow > N - 1) brow = N - 1;
      gload_lds16(A  + (size_t)arow * K + k0 + skoff, &As[r * 32 + skoff]);
      gload_lds16(Bt + (size_t)brow * K + k0 + skoff, &Bs[r * 32 + skoff]);
    }
    asm volatile("s_waitcnt vmcnt(0)" ::: "memory");
    __syncthreads();
    const int lrow = lane & 15, lk = (lane >> 4) * 8;
    bf16x8 af[4], bfr[4];
    #pragma unroll
    for (int mi = 0; mi < 4; ++mi)
      af[mi] = *(const bf16x8*)&As[(wr * 64 + mi * 16 + lrow) * 32 + lk];
    #pragma unroll
    for (int ni = 0; ni < 4; ++ni)
      bfr[ni] = *(const bf16x8*)&Bs[(wc * 64 + ni * 16 + lrow) * 32 + lk];
    #pragma unroll
    for (int mi = 0; mi < 4; ++mi)
      #pragma unroll
      for (int ni = 0; ni < 4; ++ni)
        acc[mi][ni] = __builtin_amdgcn_mfma_f32_16x16x32_bf16(af[mi], bfr[ni], acc[mi][ni], 0, 0, 0);
    __syncthreads();
  }
  const int lcol = lane & 15, rgrp = lane >> 4;
  #pragma unroll
  for (int mi = 0; mi < 4; ++mi)
    #pragma unroll
    for (int ni = 0; ni < 4; ++ni) {
      const int col = col0 + wc * 64 + ni * 16 + lcol;
      if (col >= N) continue;
      const int rbase = row0 + wr * 64 + mi * 16 + rgrp * 4;
      #pragma unroll
      for (int r = 0; r < 4; ++r) {
        const int rr = rbase + r;
        if (rr >= M) continue;
        fout[(size_t)rr * N + col] = acc[mi][ni][r];
      }
    }
}

// ---------------- LayerNorm over bf16 t: one wave per token ----------------
__global__ __launch_bounds__(256) void ln_kernel(
    const bf16_t* __restrict__ t, const float* __restrict__ w,
    const float* __restrict__ b, bf16_t* __restrict__ y)
{
  const int token = blockIdx.x * 4 + (threadIdx.x >> 6);
  const int lane  = threadIdx.x & 63;
  const bf16_t* xp = t + (size_t)token * EDIM;
  const bf16x8 a8 = *(const bf16x8*)(xp + lane * 8);
  const bf16x4 a4 = *(const bf16x4*)(xp + 512 + lane * 4);
  float va[12];
  #pragma unroll
  for (int j = 0; j < 8; ++j) va[j] = (float)a8[j];
  #pragma unroll
  for (int j = 0; j < 4; ++j) va[8 + j] = (float)a4[j];
  float s = 0.f;
  #pragma unroll
  for (int j = 0; j < 12; ++j) s += va[j];
  #pragma unroll
  for (int off = 32; off; off >>= 1) s += __shfl_xor(s, off);
  const float mu = s * (1.f / 768.f);
  float q = 0.f;
  #pragma unroll
  for (int j = 0; j < 12; ++j) { const float d = va[j] - mu; q += d * d; }
  #pragma unroll
  for (int off = 32; off; off >>= 1) q += __shfl_xor(q, off);
  const float rs = rsqrtf(q * (1.f / 768.f) + 1e-6f);

  bf16_t* yp = y + (size_t)token * EDIM;
  {
    const int e0 = lane * 8;
    const float4 w0 = ((const float4*)(w + e0))[0];
    const float4 w1 = ((const float4*)(w + e0))[1];
    const float4 b0 = ((const float4*)(b + e0))[0];
    const float4 b1 = ((const float4*)(b + e0))[1];
    bf16x8 o;
    o[0] = (bf16_t)((va[0] - mu) * rs * w0.x + b0.x);
    o[1] = (bf16_t)((va[1] - mu) * rs * w0.y + b0.y);
    o[2] = (bf16_t)((va[2] - mu) * rs * w0.z + b0.z);
    o[3] = (bf16_t)((va[3] - mu) * rs * w0.w + b0.w);
    o[4] = (bf16_t)((va[4] - mu) * rs * w1.x + b1.x);
    o[5] = (bf16_t)((va[5] - mu) * rs * w1.y + b1.y);
    o[6] = (bf16_t)((va[6] - mu) * rs * w1.z + b1.z);
    o[7] = (bf16_t)((va[7] - mu) * rs * w1.w + b1.w);
    *(bf16x8*)(yp + e0) = o;
  }
  {
    const int e0 = 512 + lane * 4;
    const float4 w0 = *(const float4*)(w + e0);
    const float4 b0 = *(const float4*)(b + e0);
    bf16x4 o;
    o[0] = (bf16_t)((va[8]  - mu) * rs * w0.x + b0.x);
    o[1] = (bf16_t)((va[9]  - mu) * rs * w0.y + b0.y);
    o[2] = (bf16_t)((va[10] - mu) * rs * w0.z + b0.z);
    o[3] = (bf16_t)((va[11] - mu) * rs * w0.w + b0.w);
    *(bf16x4*)(yp + e0) = o;
  }
}

// ---------------- row-wise attention: block per (b_local, s1, h) -----------
__global__ __launch_bounds__(256) void attn_kernel(
    const bf16_t* __restrict__ qkv, bf16_t* __restrict__ o)
{
  const int blk = blockIdx.x;
  const int h  = blk % 12;
  const int bs = blk / 12;
  const int s1 = bs % SDIM;
  const int b  = bs / SDIM;
  __shared__ float Qs[SDIM][65], Ks[SDIM][65], Vs[SDIM][65], Ps[SDIM][44];
  const int tid = threadIdx.x;
  const size_t base = ((size_t)b * LLEN + (size_t)s1 * SDIM);

  for (int idx = tid; idx < SDIM * 8; idx += 256) {
    const int m = idx >> 3, c = idx & 7;
    const bf16_t* p = qkv + (base + m) * 2304 + h * 64 + c * 8;
    const bf16x8 qv = *(const bf16x8*)(p);
    const bf16x8 kv = *(const bf16x8*)(p + 768);
    const bf16x8 vv = *(const bf16x8*)(p + 1536);
    #pragma unroll
    for (int j = 0; j < 8; ++j) {
      Qs[m][c * 8 + j] = (float)qv[j];
      Ks[m][c * 8 + j] = (float)kv[j];
      Vs[m][c * 8 + j] = (float)vv[j];
    }
  }
  __syncthreads();

  for (int idx = tid; idx < SDIM * SDIM; idx += 256) {
    const int n = idx / SDIM, m = idx % SDIM;
    float s = 0.f;
    #pragma unroll
    for (int d = 0; d < 64; ++d) s += Qs[n][d] * Ks[m][d];
    Ps[n][m] = s * 0.125f;
  }
  __syncthreads();

  {
    const int row = tid >> 2, sub = tid & 3;
    if (row < SDIM) {
      float mx = -1e30f;
      for (int m = sub; m < SDIM; m += 4) mx = fmaxf(mx, Ps[row][m]);
      mx = fmaxf(mx, __shfl_xor(mx, 1));
      mx = fmaxf(mx, __shfl_xor(mx, 2));
      float sum = 0.f;
      for (int m = sub; m < SDIM; m += 4) {
        const float e = __expf(Ps[row][m] - mx);
        Ps[row][m] = e;
        sum += e;
      }
      sum += __shfl_xor(sum, 1);
      sum += __shfl_xor(sum, 2);
      const float inv = 1.f / sum;
      for (int m = sub; m < SDIM; m += 4) Ps[row][m] *= inv;
    }
  }
  __syncthreads();

  for (int idx = tid; idx < SDIM * 64; idx += 256) {
    const int n = idx >> 6, d = idx & 63;
    float s = 0.f;
    #pragma unroll
    for (int m = 0; m < SDIM; ++m) s += Ps[n][m] * Vs[m][d];
    o[(base + n) * EDIM + h * 64 + d] = (bf16_t)s;
  }
}

// ---------------- transpose fp32(KxN) -> bf16(NxK) ----------------
__global__ __launch_bounds__(256) void transpose_kernel(
    const float* __restrict__ in, bf16_t* __restrict__ out, int K, int N)
{
  __shared__ float tile[32][33];
  const int k0 = blockIdx.x * 32, n0 = blockIdx.y * 32;
  const int tx = threadIdx.x & 31, ty = threadIdx.x >> 5;
  #pragma unroll
  for (int i = 0; i < 32; i += 8) {
    const int k = k0 + ty + i, n = n0 + tx;
    if (k < K && n < N) tile[ty + i][tx] = in[(size_t)k * N + n];
  }
  __syncthreads();
  #pragma unroll
  for (int i = 0; i < 32; i += 8) {
    const int n = n0 + ty + i, k = k0 + tx;
    if (n < N && k < K) out[(size_t)n * K + k] = (bf16_t)tile[tx][ty + i];
  }
}

// ---------------- im2col for conv1 chunk (pad K 1200->1216) ----------------
__global__ __launch_bounds__(256) void im2col_kernel(
    const float* __restrict__ x, bf16_t* __restrict__ col, int tok0, int ntok)
{
  const size_t idx = (size_t)blockIdx.x * 256 + threadIdx.x;
  if (idx >= (size_t)ntok * 1216) return;
  const int kk = (int)(idx % 1216);
  const size_t tok = tok0 + idx / 1216;
  const int b = (int)(tok / LLEN), l = (int)(tok % LLEN);
  const int s1 = l / SDIM, s2 = l % SDIM;
  float v = 0.f;
  if (kk < 1200) {
    const int cin = kk / 100, r = kk % 100, ky = r / 10, kx = r % 10;
    const int iy = s1 - 5 + ky, ix = s2 - 5 + kx;
    if (iy >= 0 && iy < 40 && ix >= 0 && ix < 40)
      v = x[((size_t)(b * 12 + cin) * 40 + iy) * 40 + ix];
  }
  col[idx] = (bf16_t)v;
}

__global__ __launch_bounds__(256) void convw_kernel(
    const float* __restrict__ w, bf16_t* __restrict__ out)
{
  const int idx = blockIdx.x * 256 + threadIdx.x;
  const int kk = idx % 1216, e = idx / 1216;
  const float v = (kk < 1200) ? w[(size_t)e * 1200 + kk] : 0.f;
  out[idx] = (bf16_t)v;
}

__global__ __launch_bounds__(256) void tconvw_kernel(
    const float* __restrict__ w, bf16_t* __restrict__ out)
{
  const int idx = blockIdx.x * 256 + threadIdx.x;  // 100*768
  const int e = idx % 768, tap = idx / 768;
  const int ky = tap / 10, kx = tap % 10;
  out[idx] = (bf16_t)w[(size_t)e * 100 + (9 - ky) * 10 + (9 - kx)];
}

// ---------------- final gather ----------------
__global__ __launch_bounds__(256) void outconv_kernel(
    const float* __restrict__ g, const float* __restrict__ tb,
    float* __restrict__ out)
{
  const int idx = blockIdx.x * 256 + threadIdx.x;
  if (idx >= 16 * 40 * 40) return;
  const int x = idx % 40, y = (idx / 40) % 40, b = idx / 1600;
  float s = tb[0];
  #pragma unroll
  for (int ky = 0; ky < 10; ++ky) {
    const int ty_ = y - 4 + ky;
    if (ty_ < 0 || ty_ >= SDIM) continue;
    #pragma unroll
    for (int kx = 0; kx < 10; ++kx) {
      const int tx_ = x - 4 + kx;
      if (tx_ < 0 || tx_ >= SDIM) continue;
      s += g[((size_t)b * LLEN + ty_ * SDIM + tx_) * 100 + ky * 10 + kx];
    }
  }
  out[idx] = s;
}

// ============================================================================
extern "C" void kernel_launch(void* const* d_in, const int* in_sizes, int n_in,
                              void* d_out, int out_size, void* d_ws, size_t ws_size,
                              hipStream_t stream)
{
  const float* x       = (const float*)d_in[0];
  const float* conv_w  = (const float*)d_in[1];
  const float* conv_b  = (const float*)d_in[2];
  const float* pos     = (const float*)d_in[3];
  const float* ln1_w   = (const float*)d_in[4];
  const float* ln1_b   = (const float*)d_in[5];
  const float* qkv_w   = (const float*)d_in[6];
  const float* qkv_b   = (const float*)d_in[7];
  const float* proj_w  = (const float*)d_in[8];
  const float* proj_b  = (const float*)d_in[9];
  const float* ln2_w   = (const float*)d_in[10];
  const float* ln2_b   = (const float*)d_in[11];
  const float* fc1_w   = (const float*)d_in[12];
  const float* fc1_b   = (const float*)d_in[13];
  const float* fc2_w   = (const float*)d_in[14];
  const float* fc2_b   = (const float*)d_in[15];
  const float* lnf_w   = (const float*)d_in[16];
  const float* lnf_b   = (const float*)d_in[17];
  const float* tconv_w = (const float*)d_in[18];
  const float* tconv_b = (const float*)d_in[19];
  float* out = (float*)d_out;

  // ---- workspace tiers (bf16 t): nch=1 262MB / nch=2 180MB / nch=4 138MB
  const int nch = (ws_size >= 262200000UL) ? 1
                : (ws_size >= 179500000UL) ? 2 : 4;
  const int cht = TOKENS / nch;

  char* p = (char*)d_ws;
  auto alloc = [&](size_t bytes) {
    char* r = p;
    p += (bytes + 255) & ~(size_t)255;
    return r;
  };
  bf16_t* wbuf = (bf16_t*)alloc((size_t)768 * 9216 * 2);
  bf16_t* t    = (bf16_t*)alloc((size_t)TOKENS * EDIM * 2);
  bf16_t* ybuf = (bf16_t*)alloc((size_t)TOKENS * EDIM * 2);
  bf16_t* hbuf = (bf16_t*)alloc((size_t)cht * 3072 * 2);

  bf16_t* Wq = wbuf;
  bf16_t* Wp = Wq + (size_t)2304 * 768;
  bf16_t* W1 = Wp + (size_t)768 * 768;
  bf16_t* W2 = W1 + (size_t)3072 * 768;

  auto g4 = [&](int epi, const bf16_t* A, const bf16_t* Bt,
                const float* bias, bf16_t* bo, const float* pe,
                int M, int N, int K) {
    const int mtiles = (M + 127) / 128;
    const int ntn = N / 128;
    const int nwg = mtiles * ntn;
    switch (epi) {
      case EPI_T_POS: gemm4_kernel<EPI_T_POS><<<nwg, 256, 0, stream>>>(A, Bt, bias, nullptr, bo, pe, M, N, K, ntn, nwg, mtiles); break;
      case EPI_BF16:  gemm4_kernel<EPI_BF16 ><<<nwg, 256, 0, stream>>>(A, Bt, bias, nullptr, bo, pe, M, N, K, ntn, nwg, mtiles); break;
      case EPI_ADD_T: gemm4_kernel<EPI_ADD_T><<<nwg, 256, 0, stream>>>(A, Bt, bias, nullptr, bo, pe, M, N, K, ntn, nwg, mtiles); break;
      default:        gemm4_kernel<EPI_GELU ><<<nwg, 256, 0, stream>>>(A, Bt, bias, nullptr, bo, pe, M, N, K, ntn, nwg, mtiles); break;
    }
  };

  // ---- conv1 as chunked im2col GEMM -> t (+bias +pos_embed), bf16 ----
  convw_kernel<<<(768 * 1216) / 256, 256, 0, stream>>>(conv_w, wbuf);
  for (int c = 0; c < nch; ++c) {
    const int tok0 = c * cht;
    im2col_kernel<<<(unsigned)(((size_t)cht * 1216 + 255) / 256), 256, 0, stream>>>(x, hbuf, tok0, cht);
    g4(EPI_T_POS, hbuf, wbuf, conv_b, t + (size_t)tok0 * EDIM, pos, cht, EDIM, 1216);
  }

  // ---- transformer layers ----
  for (int i = 0; i < 12; ++i) {
    transpose_kernel<<<dim3(24, 72), 256, 0, stream>>>(qkv_w + (size_t)i * 768 * 2304, Wq, 768, 2304);
    transpose_kernel<<<dim3(24, 24), 256, 0, stream>>>(proj_w + (size_t)i * 768 * 768, Wp, 768, 768);
    transpose_kernel<<<dim3(24, 96), 256, 0, stream>>>(fc1_w + (size_t)i * 768 * 3072, W1, 768, 3072);
    transpose_kernel<<<dim3(96, 24), 256, 0, stream>>>(fc2_w + (size_t)i * 3072 * 768, W2, 3072, 768);

    ln_kernel<<<TOKENS / 4, 256, 0, stream>>>(t, ln1_w + i * EDIM, ln1_b + i * EDIM, ybuf);
    for (int c = 0; c < nch; ++c) {
      const size_t ro = (size_t)c * cht;
      g4(EPI_BF16, ybuf + ro * EDIM, Wq, qkv_b + i * 2304, hbuf, nullptr, cht, 2304, 768);
      attn_kernel<<<(16 / nch) * SDIM * 12, 256, 0, stream>>>(hbuf, ybuf + ro * EDIM);
    }
    g4(EPI_ADD_T, ybuf, Wp, proj_b + i * EDIM, t, nullptr, TOKENS, EDIM, 768);

    ln_kernel<<<TOKENS / 4, 256, 0, stream>>>(t, ln2_w + i * EDIM, ln2_b + i * EDIM, ybuf);
    for (int c = 0; c < nch; ++c) {
      const size_t ro = (size_t)c * cht;
      g4(EPI_GELU, ybuf + ro * EDIM, W1, fc1_b + i * 3072, hbuf, nullptr, cht, 3072, 768);
      g4(EPI_ADD_T, hbuf, W2, fc2_b + i * EDIM, t + ro * EDIM, nullptr, cht, EDIM, 3072);
    }
  }

  // ---- final LN + tconv head ----
  ln_kernel<<<TOKENS / 4, 256, 0, stream>>>(t, lnf_w, lnf_b, ybuf);
  tconvw_kernel<<<(100 * 768) / 256, 256, 0, stream>>>(tconv_w, wbuf);
  gemm128_f32<<<dim3((TOKENS + 127) / 128, 1), 256, 0, stream>>>(ybuf, wbuf, (float*)hbuf, TOKENS, 100, 768);
  outconv_kernel<<<100, 256, 0, stream>>>((const float*)hbuf, tconv_b, out);
}